// Round 18
// baseline (136.412 us; speedup 1.0000x reference)
//
#include <hip/hip_runtime.h>
#include <hip/hip_bf16.h>

#define D_MODEL 1024
#define NHEADS  16
#define HDIM    64
#define SEQ     2048
#define BATCH   2
#define MROWS   (BATCH * SEQ)   // 4096
#define CHELEM  ((size_t)BATCH * NHEADS * SEQ * HDIM)  // 4194304

typedef __bf16 bf16x8 __attribute__((ext_vector_type(8)));
typedef float  f32x4  __attribute__((ext_vector_type(4)));

__device__ __forceinline__ unsigned short f2bf(float f) {
  unsigned u = __builtin_bit_cast(unsigned, f);
  return (unsigned short)((u + 0x7fffu + ((u >> 16) & 1u)) >> 16);
}

__device__ __forceinline__ float fexp2(float x) {
#if __has_builtin(__builtin_amdgcn_exp2f)
  return __builtin_amdgcn_exp2f(x);
#else
  return __expf(x * 0.6931471805599453f);
#endif
}

__device__ __forceinline__ f32x4 mfma16(bf16x8 a, bf16x8 b, f32x4 c) {
  return __builtin_amdgcn_mfma_f32_16x16x32_bf16(a, b, c, 0, 0, 0);
}

__device__ __forceinline__ void gll16(const unsigned short* g, unsigned short* l) {
  __builtin_amdgcn_global_load_lds(
      (const __attribute__((address_space(1))) unsigned*)g,
      (__attribute__((address_space(3))) unsigned*)l, 16, 0, 0);
}

__global__ void cvt_f32_bf16(const float* __restrict__ in,
                             unsigned short* __restrict__ out, int n4) {
  int i = blockIdx.x * blockDim.x + threadIdx.x;
  if (i >= n4) return;
  float4 v = reinterpret_cast<const float4*>(in)[i];
  ushort4 o;
  o.x = f2bf(v.x); o.y = f2bf(v.y); o.z = f2bf(v.z); o.w = f2bf(v.w);
  reinterpret_cast<ushort4*>(out)[i] = o;
}

// fused conversion of the 4 weight matrices (saves 3 launches)
__global__ void cvt_w4(const float* __restrict__ s0, const float* __restrict__ s1,
                       const float* __restrict__ s2, const float* __restrict__ s3,
                       unsigned short* __restrict__ d0, unsigned short* __restrict__ d1,
                       unsigned short* __restrict__ d2, unsigned short* __restrict__ d3) {
  int i = blockIdx.x * blockDim.x + threadIdx.x;  // n4 = D*D/4
  const int y = blockIdx.y;
  const float* s = (y == 0) ? s0 : (y == 1) ? s1 : (y == 2) ? s2 : s3;
  unsigned short* d = (y == 0) ? d0 : (y == 1) ? d1 : (y == 2) ? d2 : d3;
  float4 v = reinterpret_cast<const float4*>(s)[i];
  ushort4 o;
  o.x = f2bf(v.x); o.y = f2bf(v.y); o.z = f2bf(v.z); o.w = f2bf(v.w);
  reinterpret_cast<ushort4*>(d)[i] = o;
}

// C = A[M,K] * Bt[N,K]^T + bias.  BK=64 (halved barrier count vs BK=32),
// LDS tiles [128][64] with the r12-proven chunk^=(row&7) swizzle:
// pre-swizzled gll16 source + linear dest + swizzled ds_read_b128 -> 0
// conflicts.  32 MFMA per barrier interval.
// MODE 2: out f32 row-major [M,N]  (final projection, bias=b0)
// MODE 3: fused QKV: N=3072; chunk 0->Q [B,H,S,64] (PRE-SCALED by
//         0.125*log2e for exp2-domain softmax), 1->K, 2->V^T [B,H,64,S]
template <int MODE>
__global__ __launch_bounds__(256) void gemm_bt2(
    const unsigned short* __restrict__ A,
    const unsigned short* __restrict__ Bt,
    const float* __restrict__ b0, const float* __restrict__ b1,
    const float* __restrict__ b2,
    void* __restrict__ outp, int M, int N, int K) {
  __shared__ __align__(16) unsigned short lA[128 * 64];  // 16KB
  __shared__ __align__(16) unsigned short lB[128 * 64];  // 16KB
  const int tid = threadIdx.x;
  const int m0 = blockIdx.y * 128, n0 = blockIdx.x * 128;
  const int lane = tid & 63, wid = tid >> 6;
  const int wr = wid >> 1, wc = wid & 1;
  const int fr = lane & 15, g = lane >> 4;

  // staging: wave wid, call q covers rows q*32 + wid*8 + (lane>>3),
  // chunk lane&7 pre-swizzled by row&7 = lane>>3.
  const int srow = wid * 8 + (lane >> 3);
  const int scol = ((lane & 7) ^ (lane >> 3)) * 8;
  const unsigned short* gA = A + (size_t)(m0 + srow) * K + scol;
  const unsigned short* gB = Bt + (size_t)(n0 + srow) * K + scol;
  unsigned short* lAw = lA + wid * 8 * 64;
  unsigned short* lBw = lB + wid * 8 * 64;

  // read swizzle: k-subtile kk chunk = (kk*4+g)^(fr&7); rsw1 = rsw0^32
  const int rsw0 = ((g ^ (fr & 7)) << 3);
  const int rsw1 = rsw0 ^ 32;

  f32x4 acc[4][4];
#pragma unroll
  for (int i = 0; i < 4; ++i)
#pragma unroll
    for (int j = 0; j < 4; ++j) acc[i][j] = (f32x4){0.f, 0.f, 0.f, 0.f};

  for (int kt = 0; kt < K; kt += 64) {
#pragma unroll
    for (int q = 0; q < 4; ++q) {
      gll16(gA + (size_t)(q * 32) * K + kt, lAw + q * 32 * 64);
      gll16(gB + (size_t)(q * 32) * K + kt, lBw + q * 32 * 64);
    }
    __syncthreads();
    bf16x8 af[2][4], bfv[2][4];
#pragma unroll
    for (int i = 0; i < 4; ++i) {
      const int rowa = (wr * 64 + i * 16 + fr) * 64;
      af[0][i] = *reinterpret_cast<const bf16x8*>(&lA[rowa + rsw0]);
      af[1][i] = *reinterpret_cast<const bf16x8*>(&lA[rowa + rsw1]);
    }
#pragma unroll
    for (int j = 0; j < 4; ++j) {
      const int rowb = (wc * 64 + j * 16 + fr) * 64;
      bfv[0][j] = *reinterpret_cast<const bf16x8*>(&lB[rowb + rsw0]);
      bfv[1][j] = *reinterpret_cast<const bf16x8*>(&lB[rowb + rsw1]);
    }
#pragma unroll
    for (int kk = 0; kk < 2; ++kk)
#pragma unroll
      for (int i = 0; i < 4; ++i)
#pragma unroll
        for (int j = 0; j < 4; ++j)
          acc[i][j] = mfma16(af[kk][i], bfv[kk][j], acc[i][j]);
    __syncthreads();
  }

  const int src = n0 >> 10;
  const float* bp = (MODE == 2) ? b0 : (src == 0 ? b0 : (src == 1 ? b1 : b2));
#pragma unroll
  for (int i = 0; i < 4; ++i)
#pragma unroll
    for (int j = 0; j < 4; ++j)
#pragma unroll
      for (int r = 0; r < 4; ++r) {
        int m = m0 + wr * 64 + i * 16 + g * 4 + r;
        int n = n0 + wc * 64 + j * 16 + fr;
        if (MODE == 2) {
          float val = acc[i][j][r] + bp[n];
          reinterpret_cast<float*>(outp)[(size_t)m * N + n] = val;
        } else {
          int within = n & 1023;
          float val = acc[i][j][r] + bp[within];
          if (src == 0) val *= 0.1803368867f;  // 0.125 * log2(e)
          int b = m >> 11, s = m & 2047;
          int hh = within >> 6, dh = within & 63;
          size_t idx;
          if (src != 2)
            idx = ((size_t)(b * NHEADS + hh) * SEQ + s) * HDIM + dh;
          else
            idx = ((size_t)(b * NHEADS + hh) * HDIM + dh) * SEQ + s;
          reinterpret_cast<unsigned short*>(outp)[(size_t)src * CHELEM + idx] =
              f2bf(val);
        }
      }
}

// Flash attention, SWAPPED-OPERAND (S' = K*Q^T, O^T = V^T*P^T): P is
// lane-local for q = fr -> NO P LDS round-trip, scalar per-lane m/l,
// in-lane P pack with k-permutation pi applied to both PV operands
// (exact). V fragments read as 2x ds_read_b64 at pi-matched swizzled
// chunks. Block-cooperative LDS staging, defer-max, mirror-balanced
// two passes, XCD slab mapping.  (r16 kernel, verbatim — proven 48.4us.)
// Q,K: [B,H,S,64] bf16 ; Vt: [B,H,64,S] bf16 ; O: [B,S,1024] bf16
__global__ __launch_bounds__(256) void attn_fwd12(
    const unsigned short* __restrict__ Q,
    const unsigned short* __restrict__ Km,
    const unsigned short* __restrict__ Vt,
    unsigned short* __restrict__ O) {
  const int tid = threadIdx.x;
  const int lane = tid & 63, wid = tid >> 6;
  const int fr = lane & 15, g = lane >> 4;
  // XCD-grouped decode: lin%8 = XCD; 16 blocks per (b,h) slab on one XCD.
  const int lin = blockIdx.x;            // 0..511
  const int c = lin & 7;
  const int t = lin >> 3;                // 0..63
  const int j = t & 15;                  // block's pair index 0..15
  const int sgrp = t >> 4;               // 0..3
  const int slab = sgrp * 8 + c;         // 0..31
  const int b = slab >> 4, h = slab & 15;
  const int bh = b * NHEADS + h;

  __shared__ __align__(16) unsigned short lK[2][4096];   // 2 x 8KB, swizzled
  __shared__ __align__(16) unsigned short lV[2][4096];   // 2 x 8KB, swizzled

  const unsigned short* kptr = Km + (size_t)bh * SEQ * HDIM;
  const unsigned short* vptr = Vt + (size_t)bh * HDIM * SEQ;

  const int sr0 = tid >> 3;              // 0..31
  const int sch = tid & 7;
  const int schx = ((sch ^ (sr0 & 7)) << 3);  // elem offset of 16B chunk
  const int kswz0 = ((g ^ (fr & 7)) << 3);        // ch = g
  const int kswz1 = (((4 + g) ^ (fr & 7)) << 3);  // ch = 4+g
  // V b64 swizzled chunk offsets (elem units), per blk: lo=ch 4b+(g>>1),
  // hi=ch 4b+2+(g>>1); within-chunk half (g&1)*4
  const int g2 = g >> 1, gh = (g & 1) * 4;
  const int vlo0 = (((0 + g2) ^ (fr & 7)) << 3) + gh;   // blk0 lo
  const int vhi0 = (((2 + g2) ^ (fr & 7)) << 3) + gh;   // blk0 hi
  const int vlo1 = (((4 + g2) ^ (fr & 7)) << 3) + gh;   // blk1 lo
  const int vhi1 = (((6 + g2) ^ (fr & 7)) << 3) + gh;   // blk1 hi

#define STAGE(BI, N0)                                                       \
  { gll16(kptr + (size_t)((N0) + sr0) * HDIM + schx, &lK[BI][wid * 512]);   \
    gll16(kptr + (size_t)((N0) + sr0 + 32) * HDIM + schx,                   \
          &lK[BI][2048 + wid * 512]);                                       \
    gll16(vptr + (size_t)sr0 * SEQ + (N0) + schx, &lV[BI][wid * 512]);      \
    gll16(vptr + (size_t)(sr0 + 32) * SEQ + (N0) + schx,                    \
          &lV[BI][2048 + wid * 512]); }

#pragma unroll 1
  for (int pass = 0; pass < 2; ++pass) {
    const int qt = pass ? (124 - 4 * j + wid) : (4 * j + wid);
    const int q0 = qt * 16;
    const int nkt = pass ? (32 - j) : (j + 1);  // same for all 4 waves
    const int qg = q0 + fr;  // this lane's q row

    const unsigned short* qb = Q + ((size_t)bh * SEQ + qg) * HDIM + g * 8;
    bf16x8 qa0 = *reinterpret_cast<const bf16x8*>(qb);        // d 0..31
    bf16x8 qa1 = *reinterpret_cast<const bf16x8*>(qb + 32);   // d 32..63

    f32x4 oacc[4];
#pragma unroll
    for (int i = 0; i < 4; ++i) oacc[i] = (f32x4){0.f, 0.f, 0.f, 0.f};
    float mreg = -3e30f;
    float lrow = 0.f;

    STAGE(0, 0);
    __syncthreads();

    for (int kt = 0; kt < nkt; ++kt) {
      const int bi = kt & 1;
      if (kt + 1 < nkt) STAGE(bi ^ 1, (kt + 1) * 64);
      const int n0 = kt * 64;
      // K fragments as A-operand: lane holds K[cc*16+fr][d = g*8..]
      bf16x8 kf0[4], kf1[4];
#pragma unroll
      for (int cc = 0; cc < 4; ++cc) {
        kf0[cc] = *reinterpret_cast<const bf16x8*>(
            &lK[bi][(cc * 16 + fr) * 64 + kswz0]);
        kf1[cc] = *reinterpret_cast<const bf16x8*>(
            &lK[bi][(cc * 16 + fr) * 64 + kswz1]);
      }
      // S' = K * Q^T: lane (fr,g) holds S'[key=cc*16+g*4+r][q=fr]
      f32x4 s[4];
#pragma unroll
      for (int cc = 0; cc < 4; ++cc) {
        s[cc] = (f32x4){0.f, 0.f, 0.f, 0.f};
        s[cc] = mfma16(kf0[cc], qa0, s[cc]);
        s[cc] = mfma16(kf1[cc], qa1, s[cc]);
      }
      // (last-tile-only) mask; per-lane max (log2 domain, Q pre-scaled)
      float sv[4][4];
      float lmax = -3e30f;
      if (kt == nkt - 1) {
#pragma unroll
        for (int cc = 0; cc < 4; ++cc)
#pragma unroll
          for (int r = 0; r < 4; ++r) {
            sv[cc][r] =
                (n0 + cc * 16 + g * 4 + r <= qg) ? s[cc][r] : -1e30f;
            lmax = fmaxf(lmax, sv[cc][r]);
          }
      } else {
#pragma unroll
        for (int cc = 0; cc < 4; ++cc)
#pragma unroll
          for (int r = 0; r < 4; ++r) {
            sv[cc][r] = s[cc][r];
            lmax = fmaxf(lmax, sv[cc][r]);
          }
      }
      // defer-max: scalar per-lane check; rescale reduces over g (2 shfl)
      if (!__all(lmax - mreg <= 11.5f)) {
        float tm = lmax;
        tm = fmaxf(tm, __shfl_xor(tm, 16, 64));
        tm = fmaxf(tm, __shfl_xor(tm, 32, 64));
        const float mn = fmaxf(mreg, tm);
        const float al = fexp2(mreg - mn);
        mreg = mn;
        lrow *= al;
#pragma unroll
        for (int nf = 0; nf < 4; ++nf) oacc[nf] *= al;
      }
      // P = 2^(sv - m), in-lane pack (pi: slot j<4 -> cc=2blk, j>=4 -> 2blk+1)
      union { __bf16 e[8]; bf16x8 v; } pk0, pk1;
#pragma unroll
      for (int r = 0; r < 4; ++r) {
        float p0 = fexp2(sv[0][r] - mreg);
        float p1 = fexp2(sv[1][r] - mreg);
        float p2 = fexp2(sv[2][r] - mreg);
        float p3 = fexp2(sv[3][r] - mreg);
        lrow += (p0 + p1) + (p2 + p3);
        pk0.e[r] = (__bf16)p0; pk0.e[4 + r] = (__bf16)p1;
        pk1.e[r] = (__bf16)p2; pk1.e[4 + r] = (__bf16)p3;
      }
      // O^T += V^T * P^T with pi-matched V fragments (2x b64 each)
#pragma unroll
      for (int nf = 0; nf < 4; ++nf) {
        const int vrow = (nf * 16 + fr) * 64;
        union { unsigned long long d[2]; bf16x8 v; } v0, v1;
        v0.d[0] = *reinterpret_cast<const unsigned long long*>(&lV[bi][vrow + vlo0]);
        v0.d[1] = *reinterpret_cast<const unsigned long long*>(&lV[bi][vrow + vhi0]);
        v1.d[0] = *reinterpret_cast<const unsigned long long*>(&lV[bi][vrow + vlo1]);
        v1.d[1] = *reinterpret_cast<const unsigned long long*>(&lV[bi][vrow + vhi1]);
        oacc[nf] = mfma16(v0.v, pk0.v, oacc[nf]);
        oacc[nf] = mfma16(v1.v, pk1.v, oacc[nf]);
      }
      __syncthreads();  // staged kt+1 complete; reads of buf bi done
    }

    // epilogue: lsum reduce over g (2 shfl); O^T -> O via direct stores
    float ls = lrow;
    ls += __shfl_xor(ls, 16, 64);
    ls += __shfl_xor(ls, 32, 64);
    const float inv = 1.f / ls;
    const size_t obase = ((size_t)b * SEQ + qg) * D_MODEL + h * HDIM + g * 4;
#pragma unroll
    for (int nf = 0; nf < 4; ++nf) {
      ushort4 o4;
      o4.x = f2bf(oacc[nf][0] * inv);
      o4.y = f2bf(oacc[nf][1] * inv);
      o4.z = f2bf(oacc[nf][2] * inv);
      o4.w = f2bf(oacc[nf][3] * inv);
      *reinterpret_cast<ushort4*>(&O[obase + nf * 16]) = o4;
    }
  }
#undef STAGE
}

extern "C" void kernel_launch(void* const* d_in, const int* in_sizes, int n_in,
                              void* d_out, int out_size, void* d_ws,
                              size_t ws_size, hipStream_t stream) {
  const float* x  = (const float*)d_in[0];
  const float* wq = (const float*)d_in[1];
  const float* bq = (const float*)d_in[2];
  const float* wk = (const float*)d_in[3];
  const float* bk = (const float*)d_in[4];
  const float* wv = (const float*)d_in[5];
  const float* bv = (const float*)d_in[6];
  const float* wo = (const float*)d_in[7];
  const float* bo = (const float*)d_in[8];
  float* out = (float*)d_out;

  char* w = (char*)d_ws;
  unsigned short* xb    = (unsigned short*)w; w += (size_t)MROWS * D_MODEL * 2;
  unsigned short* wqkvb = (unsigned short*)w; w += (size_t)3 * D_MODEL * D_MODEL * 2;
  unsigned short* wob   = (unsigned short*)w; w += (size_t)D_MODEL * D_MODEL * 2;
  unsigned short* Qb    = (unsigned short*)w; w += CHELEM * 2 * 3;  // Q,K,Vt
  unsigned short* Ob    = (unsigned short*)w; w += (size_t)MROWS * D_MODEL * 2;
  unsigned short* Kb  = Qb + CHELEM;
  unsigned short* Vtb = Qb + 2 * CHELEM;

  {
    int n4 = MROWS * D_MODEL / 4;
    cvt_f32_bf16<<<n4 / 256, 256, 0, stream>>>(x, xb, n4);
  }
  {
    int n4 = D_MODEL * D_MODEL / 4;  // 262144 -> 1024 blocks x 4
    cvt_w4<<<dim3(n4 / 256, 4), 256, 0, stream>>>(
        wq, wk, wv, wo, wqkvb, wqkvb + (size_t)D_MODEL * D_MODEL,
        wqkvb + (size_t)2 * D_MODEL * D_MODEL, wob);
  }

  // fused QKV projection: N = 3072
  gemm_bt2<3><<<dim3(3 * D_MODEL / 128, MROWS / 128), 256, 0, stream>>>(
      xb, wqkvb, bq, bk, bv, Qb, MROWS, 3 * D_MODEL, D_MODEL);

  attn_fwd12<<<512, 256, 0, stream>>>(Qb, Kb, Vtb, Ob);

  gemm_bt2<2><<<dim3(D_MODEL / 128, MROWS / 128), 256, 0, stream>>>(
      Ob, wob, bo, bo, bo, out, MROWS, D_MODEL, D_MODEL);
}

// Round 19
// 121.786 us; speedup vs baseline: 1.1201x; 1.1201x over previous
//
#include <hip/hip_runtime.h>
#include <hip/hip_bf16.h>

#define D_MODEL 1024
#define NHEADS  16
#define HDIM    64
#define SEQ     2048
#define BATCH   2
#define MROWS   (BATCH * SEQ)   // 4096
#define CHELEM  ((size_t)BATCH * NHEADS * SEQ * HDIM)  // 4194304

typedef __bf16 bf16x8 __attribute__((ext_vector_type(8)));
typedef float  f32x4  __attribute__((ext_vector_type(4)));

__device__ __forceinline__ unsigned short f2bf(float f) {
  unsigned u = __builtin_bit_cast(unsigned, f);
  return (unsigned short)((u + 0x7fffu + ((u >> 16) & 1u)) >> 16);
}

__device__ __forceinline__ float fexp2(float x) {
#if __has_builtin(__builtin_amdgcn_exp2f)
  return __builtin_amdgcn_exp2f(x);
#else
  return __expf(x * 0.6931471805599453f);
#endif
}

__device__ __forceinline__ f32x4 mfma16(bf16x8 a, bf16x8 b, f32x4 c) {
  return __builtin_amdgcn_mfma_f32_16x16x32_bf16(a, b, c, 0, 0, 0);
}

__device__ __forceinline__ void gll16(const unsigned short* g, unsigned short* l) {
  __builtin_amdgcn_global_load_lds(
      (const __attribute__((address_space(1))) unsigned*)g,
      (__attribute__((address_space(3))) unsigned*)l, 16, 0, 0);
}

__global__ void cvt_f32_bf16(const float* __restrict__ in,
                             unsigned short* __restrict__ out, int n4) {
  int i = blockIdx.x * blockDim.x + threadIdx.x;
  if (i >= n4) return;
  float4 v = reinterpret_cast<const float4*>(in)[i];
  ushort4 o;
  o.x = f2bf(v.x); o.y = f2bf(v.y); o.z = f2bf(v.z); o.w = f2bf(v.w);
  reinterpret_cast<ushort4*>(out)[i] = o;
}

// fused conversion of the 4 weight matrices (saves 3 launches)
__global__ void cvt_w4(const float* __restrict__ s0, const float* __restrict__ s1,
                       const float* __restrict__ s2, const float* __restrict__ s3,
                       unsigned short* __restrict__ d0, unsigned short* __restrict__ d1,
                       unsigned short* __restrict__ d2, unsigned short* __restrict__ d3) {
  int i = blockIdx.x * blockDim.x + threadIdx.x;  // n4 = D*D/4
  const int y = blockIdx.y;
  const float* s = (y == 0) ? s0 : (y == 1) ? s1 : (y == 2) ? s2 : s3;
  unsigned short* d = (y == 0) ? d0 : (y == 1) ? d1 : (y == 2) ? d2 : d3;
  float4 v = reinterpret_cast<const float4*>(s)[i];
  ushort4 o;
  o.x = f2bf(v.x); o.y = f2bf(v.y); o.z = f2bf(v.z); o.w = f2bf(v.w);
  reinterpret_cast<ushort4*>(d)[i] = o;
}

// C = A[M,K] * Bt[N,K]^T + bias  (global_load_lds staging, m97 pattern,
// BK=32 — r16-proven config; 16B-chunk XOR swizzle, 0 conflicts).
// MODE 2: out f32 row-major [M,N]  (final projection, bias=b0)
// MODE 3: fused QKV: N=3072; chunk 0->Q [B,H,S,64] (PRE-SCALED by
//         0.125*log2e for exp2-domain softmax), 1->K, 2->V^T [B,H,64,S]
//         (V^T epilogue packs 4 consecutive-s values into one ushort4)
template <int MODE>
__global__ __launch_bounds__(256) void gemm_bt2(
    const unsigned short* __restrict__ A,
    const unsigned short* __restrict__ Bt,
    const float* __restrict__ b0, const float* __restrict__ b1,
    const float* __restrict__ b2,
    void* __restrict__ outp, int M, int N, int K) {
  __shared__ __align__(16) unsigned short lA[128 * 32];
  __shared__ __align__(16) unsigned short lB[128 * 32];
  const int tid = threadIdx.x;
  const int m0 = blockIdx.y * 128, n0 = blockIdx.x * 128;
  const int lane = tid & 63, wid = tid >> 6;
  const int wr = wid >> 1, wc = wid & 1;
  const int fr = lane & 15, g = lane >> 4;

  const int srow = wid * 32 + (lane >> 2);
  const int scol = ((lane & 3) ^ ((lane >> 3) & 3)) * 8;
  const unsigned short* gA = A + (size_t)(m0 + srow) * K + scol;
  const unsigned short* gB = Bt + (size_t)(n0 + srow) * K + scol;
  unsigned short* lAw = lA + wid * 1024;
  unsigned short* lBw = lB + wid * 1024;

  const int rswz = (g ^ ((fr >> 1) & 3)) * 8;

  f32x4 acc[4][4];
#pragma unroll
  for (int i = 0; i < 4; ++i)
#pragma unroll
    for (int j = 0; j < 4; ++j) acc[i][j] = (f32x4){0.f, 0.f, 0.f, 0.f};

  for (int kt = 0; kt < K; kt += 32) {
    gll16(gA + kt, lAw);
    gll16(gA + (size_t)16 * K + kt, lAw + 512);
    gll16(gB + kt, lBw);
    gll16(gB + (size_t)16 * K + kt, lBw + 512);
    __syncthreads();
    bf16x8 af[4], bfv[4];
#pragma unroll
    for (int i = 0; i < 4; ++i)
      af[i] = *reinterpret_cast<const bf16x8*>(
          &lA[(wr * 64 + i * 16 + fr) * 32 + rswz]);
#pragma unroll
    for (int j = 0; j < 4; ++j)
      bfv[j] = *reinterpret_cast<const bf16x8*>(
          &lB[(wc * 64 + j * 16 + fr) * 32 + rswz]);
#pragma unroll
    for (int i = 0; i < 4; ++i)
#pragma unroll
      for (int j = 0; j < 4; ++j)
        acc[i][j] = mfma16(af[i], bfv[j], acc[i][j]);
    __syncthreads();
  }

  const int src = n0 >> 10;
  const float* bp = (MODE == 2) ? b0 : (src == 0 ? b0 : (src == 1 ? b1 : b2));
#pragma unroll
  for (int i = 0; i < 4; ++i)
#pragma unroll
    for (int j = 0; j < 4; ++j) {
      if (MODE == 3 && src == 2) {
        // V^T: the 4 r-values are consecutive in s -> one ushort4 store
        const int mb = m0 + wr * 64 + i * 16 + g * 4;  // r = 0..3 from here
        const int n = n0 + wc * 64 + j * 16 + fr;
        const int within = n & 1023;
        const float bias = bp[within];
        const int b = mb >> 11, s0 = mb & 2047;
        const int hh = within >> 6, dh = within & 63;
        const size_t idx0 =
            ((size_t)(b * NHEADS + hh) * HDIM + dh) * SEQ + s0;
        ushort4 o4;
        o4.x = f2bf(acc[i][j][0] + bias);
        o4.y = f2bf(acc[i][j][1] + bias);
        o4.z = f2bf(acc[i][j][2] + bias);
        o4.w = f2bf(acc[i][j][3] + bias);
        *reinterpret_cast<ushort4*>(
            reinterpret_cast<unsigned short*>(outp) + 2 * CHELEM + idx0) = o4;
      } else {
#pragma unroll
        for (int r = 0; r < 4; ++r) {
          int m = m0 + wr * 64 + i * 16 + g * 4 + r;
          int n = n0 + wc * 64 + j * 16 + fr;
          if (MODE == 2) {
            float val = acc[i][j][r] + bp[n];
            reinterpret_cast<float*>(outp)[(size_t)m * N + n] = val;
          } else {
            int within = n & 1023;
            float val = acc[i][j][r] + bp[within];
            if (src == 0) val *= 0.1803368867f;  // 0.125 * log2(e)
            int b = m >> 11, s = m & 2047;
            int hh = within >> 6, dh = within & 63;
            size_t idx = ((size_t)(b * NHEADS + hh) * SEQ + s) * HDIM + dh;
            reinterpret_cast<unsigned short*>(outp)[(size_t)src * CHELEM + idx] =
                f2bf(val);
          }
        }
      }
    }
}

// Flash attention, SWAPPED-OPERAND (S' = K*Q^T, O^T = V^T*P^T): P is
// lane-local for q = fr -> NO P LDS round-trip, scalar per-lane m/l,
// in-lane P pack with k-permutation pi applied to both PV operands
// (exact). V fragments read as 2x ds_read_b64 at pi-matched swizzled
// chunks. Block-cooperative LDS staging, defer-max, mirror-balanced
// two passes, XCD slab mapping.  (r16 kernel, verbatim — proven 48.4us.)
// Q,K: [B,H,S,64] bf16 ; Vt: [B,H,64,S] bf16 ; O: [B,S,1024] bf16
__global__ __launch_bounds__(256) void attn_fwd12(
    const unsigned short* __restrict__ Q,
    const unsigned short* __restrict__ Km,
    const unsigned short* __restrict__ Vt,
    unsigned short* __restrict__ O) {
  const int tid = threadIdx.x;
  const int lane = tid & 63, wid = tid >> 6;
  const int fr = lane & 15, g = lane >> 4;
  // XCD-grouped decode: lin%8 = XCD; 16 blocks per (b,h) slab on one XCD.
  const int lin = blockIdx.x;            // 0..511
  const int c = lin & 7;
  const int t = lin >> 3;                // 0..63
  const int j = t & 15;                  // block's pair index 0..15
  const int sgrp = t >> 4;               // 0..3
  const int slab = sgrp * 8 + c;         // 0..31
  const int b = slab >> 4, h = slab & 15;
  const int bh = b * NHEADS + h;

  __shared__ __align__(16) unsigned short lK[2][4096];   // 2 x 8KB, swizzled
  __shared__ __align__(16) unsigned short lV[2][4096];   // 2 x 8KB, swizzled

  const unsigned short* kptr = Km + (size_t)bh * SEQ * HDIM;
  const unsigned short* vptr = Vt + (size_t)bh * HDIM * SEQ;

  const int sr0 = tid >> 3;              // 0..31
  const int sch = tid & 7;
  const int schx = ((sch ^ (sr0 & 7)) << 3);  // elem offset of 16B chunk
  const int kswz0 = ((g ^ (fr & 7)) << 3);        // ch = g
  const int kswz1 = (((4 + g) ^ (fr & 7)) << 3);  // ch = 4+g
  const int g2 = g >> 1, gh = (g & 1) * 4;
  const int vlo0 = (((0 + g2) ^ (fr & 7)) << 3) + gh;   // blk0 lo
  const int vhi0 = (((2 + g2) ^ (fr & 7)) << 3) + gh;   // blk0 hi
  const int vlo1 = (((4 + g2) ^ (fr & 7)) << 3) + gh;   // blk1 lo
  const int vhi1 = (((6 + g2) ^ (fr & 7)) << 3) + gh;   // blk1 hi

#define STAGE(BI, N0)                                                       \
  { gll16(kptr + (size_t)((N0) + sr0) * HDIM + schx, &lK[BI][wid * 512]);   \
    gll16(kptr + (size_t)((N0) + sr0 + 32) * HDIM + schx,                   \
          &lK[BI][2048 + wid * 512]);                                       \
    gll16(vptr + (size_t)sr0 * SEQ + (N0) + schx, &lV[BI][wid * 512]);      \
    gll16(vptr + (size_t)(sr0 + 32) * SEQ + (N0) + schx,                    \
          &lV[BI][2048 + wid * 512]); }

#pragma unroll 1
  for (int pass = 0; pass < 2; ++pass) {
    const int qt = pass ? (124 - 4 * j + wid) : (4 * j + wid);
    const int q0 = qt * 16;
    const int nkt = pass ? (32 - j) : (j + 1);  // same for all 4 waves
    const int qg = q0 + fr;  // this lane's q row

    const unsigned short* qb = Q + ((size_t)bh * SEQ + qg) * HDIM + g * 8;
    bf16x8 qa0 = *reinterpret_cast<const bf16x8*>(qb);        // d 0..31
    bf16x8 qa1 = *reinterpret_cast<const bf16x8*>(qb + 32);   // d 32..63

    f32x4 oacc[4];
#pragma unroll
    for (int i = 0; i < 4; ++i) oacc[i] = (f32x4){0.f, 0.f, 0.f, 0.f};
    float mreg = -3e30f;
    float lrow = 0.f;

    STAGE(0, 0);
    __syncthreads();

    for (int kt = 0; kt < nkt; ++kt) {
      const int bi = kt & 1;
      if (kt + 1 < nkt) STAGE(bi ^ 1, (kt + 1) * 64);
      const int n0 = kt * 64;
      // K fragments as A-operand: lane holds K[cc*16+fr][d = g*8..]
      bf16x8 kf0[4], kf1[4];
#pragma unroll
      for (int cc = 0; cc < 4; ++cc) {
        kf0[cc] = *reinterpret_cast<const bf16x8*>(
            &lK[bi][(cc * 16 + fr) * 64 + kswz0]);
        kf1[cc] = *reinterpret_cast<const bf16x8*>(
            &lK[bi][(cc * 16 + fr) * 64 + kswz1]);
      }
      // S' = K * Q^T: lane (fr,g) holds S'[key=cc*16+g*4+r][q=fr]
      f32x4 s[4];
#pragma unroll
      for (int cc = 0; cc < 4; ++cc) {
        s[cc] = (f32x4){0.f, 0.f, 0.f, 0.f};
        s[cc] = mfma16(kf0[cc], qa0, s[cc]);
        s[cc] = mfma16(kf1[cc], qa1, s[cc]);
      }
      // (last-tile-only) mask; per-lane max (log2 domain, Q pre-scaled)
      float sv[4][4];
      float lmax = -3e30f;
      if (kt == nkt - 1) {
#pragma unroll
        for (int cc = 0; cc < 4; ++cc)
#pragma unroll
          for (int r = 0; r < 4; ++r) {
            sv[cc][r] =
                (n0 + cc * 16 + g * 4 + r <= qg) ? s[cc][r] : -1e30f;
            lmax = fmaxf(lmax, sv[cc][r]);
          }
      } else {
#pragma unroll
        for (int cc = 0; cc < 4; ++cc)
#pragma unroll
          for (int r = 0; r < 4; ++r) {
            sv[cc][r] = s[cc][r];
            lmax = fmaxf(lmax, sv[cc][r]);
          }
      }
      // defer-max: scalar per-lane check; rescale reduces over g (2 shfl)
      if (!__all(lmax - mreg <= 11.5f)) {
        float tm = lmax;
        tm = fmaxf(tm, __shfl_xor(tm, 16, 64));
        tm = fmaxf(tm, __shfl_xor(tm, 32, 64));
        const float mn = fmaxf(mreg, tm);
        const float al = fexp2(mreg - mn);
        mreg = mn;
        lrow *= al;
#pragma unroll
        for (int nf = 0; nf < 4; ++nf) oacc[nf] *= al;
      }
      // P = 2^(sv - m), in-lane pack (pi: slot j<4 -> cc=2blk, j>=4 -> 2blk+1)
      union { __bf16 e[8]; bf16x8 v; } pk0, pk1;
#pragma unroll
      for (int r = 0; r < 4; ++r) {
        float p0 = fexp2(sv[0][r] - mreg);
        float p1 = fexp2(sv[1][r] - mreg);
        float p2 = fexp2(sv[2][r] - mreg);
        float p3 = fexp2(sv[3][r] - mreg);
        lrow += (p0 + p1) + (p2 + p3);
        pk0.e[r] = (__bf16)p0; pk0.e[4 + r] = (__bf16)p1;
        pk1.e[r] = (__bf16)p2; pk1.e[4 + r] = (__bf16)p3;
      }
      // O^T += V^T * P^T with pi-matched V fragments (2x b64 each)
#pragma unroll
      for (int nf = 0; nf < 4; ++nf) {
        const int vrow = (nf * 16 + fr) * 64;
        union { unsigned long long d[2]; bf16x8 v; } v0, v1;
        v0.d[0] = *reinterpret_cast<const unsigned long long*>(&lV[bi][vrow + vlo0]);
        v0.d[1] = *reinterpret_cast<const unsigned long long*>(&lV[bi][vrow + vhi0]);
        v1.d[0] = *reinterpret_cast<const unsigned long long*>(&lV[bi][vrow + vlo1]);
        v1.d[1] = *reinterpret_cast<const unsigned long long*>(&lV[bi][vrow + vhi1]);
        oacc[nf] = mfma16(v0.v, pk0.v, oacc[nf]);
        oacc[nf] = mfma16(v1.v, pk1.v, oacc[nf]);
      }
      __syncthreads();  // staged kt+1 complete; reads of buf bi done
    }

    // epilogue: lsum reduce over g (2 shfl); O^T -> O via direct stores
    float ls = lrow;
    ls += __shfl_xor(ls, 16, 64);
    ls += __shfl_xor(ls, 32, 64);
    const float inv = 1.f / ls;
    const size_t obase = ((size_t)b * SEQ + qg) * D_MODEL + h * HDIM + g * 4;
#pragma unroll
    for (int nf = 0; nf < 4; ++nf) {
      ushort4 o4;
      o4.x = f2bf(oacc[nf][0] * inv);
      o4.y = f2bf(oacc[nf][1] * inv);
      o4.z = f2bf(oacc[nf][2] * inv);
      o4.w = f2bf(oacc[nf][3] * inv);
      *reinterpret_cast<ushort4*>(&O[obase + nf * 16]) = o4;
    }
  }
#undef STAGE
}

extern "C" void kernel_launch(void* const* d_in, const int* in_sizes, int n_in,
                              void* d_out, int out_size, void* d_ws,
                              size_t ws_size, hipStream_t stream) {
  const float* x  = (const float*)d_in[0];
  const float* wq = (const float*)d_in[1];
  const float* bq = (const float*)d_in[2];
  const float* wk = (const float*)d_in[3];
  const float* bk = (const float*)d_in[4];
  const float* wv = (const float*)d_in[5];
  const float* bv = (const float*)d_in[6];
  const float* wo = (const float*)d_in[7];
  const float* bo = (const float*)d_in[8];
  float* out = (float*)d_out;

  char* w = (char*)d_ws;
  unsigned short* xb    = (unsigned short*)w; w += (size_t)MROWS * D_MODEL * 2;
  unsigned short* wqkvb = (unsigned short*)w; w += (size_t)3 * D_MODEL * D_MODEL * 2;
  unsigned short* wob   = (unsigned short*)w; w += (size_t)D_MODEL * D_MODEL * 2;
  unsigned short* Qb    = (unsigned short*)w; w += CHELEM * 2 * 3;  // Q,K,Vt
  unsigned short* Ob    = (unsigned short*)w; w += (size_t)MROWS * D_MODEL * 2;
  unsigned short* Kb  = Qb + CHELEM;
  unsigned short* Vtb = Qb + 2 * CHELEM;

  {
    int n4 = MROWS * D_MODEL / 4;
    cvt_f32_bf16<<<n4 / 256, 256, 0, stream>>>(x, xb, n4);
  }
  {
    int n4 = D_MODEL * D_MODEL / 4;  // 262144 -> 1024 blocks x 4
    cvt_w4<<<dim3(n4 / 256, 4), 256, 0, stream>>>(
        wq, wk, wv, wo, wqkvb, wqkvb + (size_t)D_MODEL * D_MODEL,
        wqkvb + (size_t)2 * D_MODEL * D_MODEL, wob);
  }

  // fused QKV projection: N = 3072
  gemm_bt2<3><<<dim3(3 * D_MODEL / 128, MROWS / 128), 256, 0, stream>>>(
      xb, wqkvb, bq, bk, bv, Qb, MROWS, 3 * D_MODEL, D_MODEL);

  attn_fwd12<<<512, 256, 0, stream>>>(Qb, Kb, Vtb, Ob);

  gemm_bt2<2><<<dim3(D_MODEL / 128, MROWS / 128), 256, 0, stream>>>(
      Ob, wob, bo, bo, bo, out, MROWS, D_MODEL, D_MODEL);
}

// Round 20
// 119.496 us; speedup vs baseline: 1.1416x; 1.0192x over previous
//
#include <hip/hip_runtime.h>
#include <hip/hip_bf16.h>

#define D_MODEL 1024
#define NHEADS  16
#define HDIM    64
#define SEQ     2048
#define BATCH   2
#define MROWS   (BATCH * SEQ)   // 4096
#define CHELEM  ((size_t)BATCH * NHEADS * SEQ * HDIM)  // 4194304

typedef __bf16 bf16x8 __attribute__((ext_vector_type(8)));
typedef float  f32x4  __attribute__((ext_vector_type(4)));

__device__ __forceinline__ unsigned short f2bf(float f) {
  unsigned u = __builtin_bit_cast(unsigned, f);
  return (unsigned short)((u + 0x7fffu + ((u >> 16) & 1u)) >> 16);
}

__device__ __forceinline__ float fexp2(float x) {
#if __has_builtin(__builtin_amdgcn_exp2f)
  return __builtin_amdgcn_exp2f(x);
#else
  return __expf(x * 0.6931471805599453f);
#endif
}

__device__ __forceinline__ f32x4 mfma16(bf16x8 a, bf16x8 b, f32x4 c) {
  return __builtin_amdgcn_mfma_f32_16x16x32_bf16(a, b, c, 0, 0, 0);
}

__device__ __forceinline__ void gll16(const unsigned short* g, unsigned short* l) {
  __builtin_amdgcn_global_load_lds(
      (const __attribute__((address_space(1))) unsigned*)g,
      (__attribute__((address_space(3))) unsigned*)l, 16, 0, 0);
}

__global__ void cvt_f32_bf16(const float* __restrict__ in,
                             unsigned short* __restrict__ out, int n4) {
  int i = blockIdx.x * blockDim.x + threadIdx.x;
  if (i >= n4) return;
  float4 v = reinterpret_cast<const float4*>(in)[i];
  ushort4 o;
  o.x = f2bf(v.x); o.y = f2bf(v.y); o.z = f2bf(v.z); o.w = f2bf(v.w);
  reinterpret_cast<ushort4*>(out)[i] = o;
}

// fused conversion of the 4 weight matrices (saves 3 launches)
__global__ void cvt_w4(const float* __restrict__ s0, const float* __restrict__ s1,
                       const float* __restrict__ s2, const float* __restrict__ s3,
                       unsigned short* __restrict__ d0, unsigned short* __restrict__ d1,
                       unsigned short* __restrict__ d2, unsigned short* __restrict__ d3) {
  int i = blockIdx.x * blockDim.x + threadIdx.x;  // n4 = D*D/4
  const int y = blockIdx.y;
  const float* s = (y == 0) ? s0 : (y == 1) ? s1 : (y == 2) ? s2 : s3;
  unsigned short* d = (y == 0) ? d0 : (y == 1) ? d1 : (y == 2) ? d2 : d3;
  float4 v = reinterpret_cast<const float4*>(s)[i];
  ushort4 o;
  o.x = f2bf(v.x); o.y = f2bf(v.y); o.z = f2bf(v.z); o.w = f2bf(v.w);
  reinterpret_cast<ushort4*>(d)[i] = o;
}

// C = A[M,K] * Bt[N,K]^T + bias  (global_load_lds staging, m97 pattern,
// BK=32 — r16-proven config; 16B-chunk XOR swizzle, 0 conflicts).
// MODE 2: out f32 row-major [M,N]  (final projection, bias=b0)
// MODE 3: fused QKV: N=3072; chunk 0->Q [B,H,S,64] (PRE-SCALED by
//         0.125*log2e for exp2-domain softmax), 1->K, 2->V^T [B,H,64,S]
//         (V^T epilogue packs 4 consecutive-s values into one ushort4)
template <int MODE>
__global__ __launch_bounds__(256) void gemm_bt2(
    const unsigned short* __restrict__ A,
    const unsigned short* __restrict__ Bt,
    const float* __restrict__ b0, const float* __restrict__ b1,
    const float* __restrict__ b2,
    void* __restrict__ outp, int M, int N, int K) {
  __shared__ __align__(16) unsigned short lA[128 * 32];
  __shared__ __align__(16) unsigned short lB[128 * 32];
  const int tid = threadIdx.x;
  const int m0 = blockIdx.y * 128, n0 = blockIdx.x * 128;
  const int lane = tid & 63, wid = tid >> 6;
  const int wr = wid >> 1, wc = wid & 1;
  const int fr = lane & 15, g = lane >> 4;

  const int srow = wid * 32 + (lane >> 2);
  const int scol = ((lane & 3) ^ ((lane >> 3) & 3)) * 8;
  const unsigned short* gA = A + (size_t)(m0 + srow) * K + scol;
  const unsigned short* gB = Bt + (size_t)(n0 + srow) * K + scol;
  unsigned short* lAw = lA + wid * 1024;
  unsigned short* lBw = lB + wid * 1024;

  const int rswz = (g ^ ((fr >> 1) & 3)) * 8;

  f32x4 acc[4][4];
#pragma unroll
  for (int i = 0; i < 4; ++i)
#pragma unroll
    for (int j = 0; j < 4; ++j) acc[i][j] = (f32x4){0.f, 0.f, 0.f, 0.f};

  for (int kt = 0; kt < K; kt += 32) {
    gll16(gA + kt, lAw);
    gll16(gA + (size_t)16 * K + kt, lAw + 512);
    gll16(gB + kt, lBw);
    gll16(gB + (size_t)16 * K + kt, lBw + 512);
    __syncthreads();
    bf16x8 af[4], bfv[4];
#pragma unroll
    for (int i = 0; i < 4; ++i)
      af[i] = *reinterpret_cast<const bf16x8*>(
          &lA[(wr * 64 + i * 16 + fr) * 32 + rswz]);
#pragma unroll
    for (int j = 0; j < 4; ++j)
      bfv[j] = *reinterpret_cast<const bf16x8*>(
          &lB[(wc * 64 + j * 16 + fr) * 32 + rswz]);
#pragma unroll
    for (int i = 0; i < 4; ++i)
#pragma unroll
      for (int j = 0; j < 4; ++j)
        acc[i][j] = mfma16(af[i], bfv[j], acc[i][j]);
    __syncthreads();
  }

  const int src = n0 >> 10;
  const float* bp = (MODE == 2) ? b0 : (src == 0 ? b0 : (src == 1 ? b1 : b2));
#pragma unroll
  for (int i = 0; i < 4; ++i)
#pragma unroll
    for (int j = 0; j < 4; ++j) {
      if (MODE == 3 && src == 2) {
        // V^T: the 4 r-values are consecutive in s -> one ushort4 store
        const int mb = m0 + wr * 64 + i * 16 + g * 4;  // r = 0..3 from here
        const int n = n0 + wc * 64 + j * 16 + fr;
        const int within = n & 1023;
        const float bias = bp[within];
        const int b = mb >> 11, s0 = mb & 2047;
        const int hh = within >> 6, dh = within & 63;
        const size_t idx0 =
            ((size_t)(b * NHEADS + hh) * HDIM + dh) * SEQ + s0;
        ushort4 o4;
        o4.x = f2bf(acc[i][j][0] + bias);
        o4.y = f2bf(acc[i][j][1] + bias);
        o4.z = f2bf(acc[i][j][2] + bias);
        o4.w = f2bf(acc[i][j][3] + bias);
        *reinterpret_cast<ushort4*>(
            reinterpret_cast<unsigned short*>(outp) + 2 * CHELEM + idx0) = o4;
      } else {
#pragma unroll
        for (int r = 0; r < 4; ++r) {
          int m = m0 + wr * 64 + i * 16 + g * 4 + r;
          int n = n0 + wc * 64 + j * 16 + fr;
          if (MODE == 2) {
            float val = acc[i][j][r] + bp[n];
            reinterpret_cast<float*>(outp)[(size_t)m * N + n] = val;
          } else {
            int within = n & 1023;
            float val = acc[i][j][r] + bp[within];
            if (src == 0) val *= 0.1803368867f;  // 0.125 * log2(e)
            int b = m >> 11, s = m & 2047;
            int hh = within >> 6, dh = within & 63;
            size_t idx = ((size_t)(b * NHEADS + hh) * SEQ + s) * HDIM + dh;
            reinterpret_cast<unsigned short*>(outp)[(size_t)src * CHELEM + idx] =
                f2bf(val);
          }
        }
      }
    }
}

// Flash attention, swapped-operand, KVBLK=128: per-tile bookkeeping (mask,
// defer-max, P-pack setup, barrier, staging issue) amortized over 2x keys;
// barriers per block 33 -> 17.  Balance preserved exactly: nkt0 = j/2+1,
// nkt1 = 16-j/2 (wid-independent), total 17 intervals for every block.
// K tile [128 keys][64 d] (8 chunks/row), V tile [64 d][128 s] (16
// chunks/row), both chunk^=(row&7) swizzled via pre-swizzled gll16 source.
// Q,K: [B,H,S,64] bf16 ; Vt: [B,H,64,S] bf16 ; O: [B,S,1024] bf16
__global__ __launch_bounds__(256) void attn_fwd14(
    const unsigned short* __restrict__ Q,
    const unsigned short* __restrict__ Km,
    const unsigned short* __restrict__ Vt,
    unsigned short* __restrict__ O) {
  const int tid = threadIdx.x;
  const int lane = tid & 63, wid = tid >> 6;
  const int fr = lane & 15, g = lane >> 4;
  // XCD-grouped decode: lin%8 = XCD; 16 blocks per (b,h) slab on one XCD.
  const int lin = blockIdx.x;            // 0..511
  const int c = lin & 7;
  const int t = lin >> 3;                // 0..63
  const int j = t & 15;                  // block's pair index 0..15
  const int sgrp = t >> 4;               // 0..3
  const int slab = sgrp * 8 + c;         // 0..31
  const int b = slab >> 4, h = slab & 15;
  const int bh = b * NHEADS + h;

  __shared__ __align__(16) unsigned short lK[2][8192];   // 2 x 16KB
  __shared__ __align__(16) unsigned short lV[2][8192];   // 2 x 16KB

  const unsigned short* kptr = Km + (size_t)bh * SEQ * HDIM;
  const unsigned short* vptr = Vt + (size_t)bh * HDIM * SEQ;

  // K staging: rows tid>>3 (+32/call), 8 chunks/row, chunk^=(row&7)
  const int srK = tid >> 3;              // 0..31
  const int schK = (((tid & 7) ^ (srK & 7)) << 3);
  // V staging: rows tid>>4 (+16/call), 16 chunks/row, chunk^=(row&7)
  const int srV = tid >> 4;              // 0..15
  const int schV = (((tid & 15) ^ (srV & 7)) << 3);
  // K fragment read chunks (8/row):
  const int kswz0 = ((g ^ (fr & 7)) << 3);        // ch = g
  const int kswz1 = (((4 + g) ^ (fr & 7)) << 3);  // ch = 4+g
  // V b64 read chunks (16/row), blk = 0..3 (32 keys each):
  const int g2 = g >> 1, gh = (g & 1) * 4;
  const int vlo0 = (((0 + g2) ^ (fr & 7)) << 3) + gh;
  const int vhi0 = (((2 + g2) ^ (fr & 7)) << 3) + gh;
  const int vlo1 = (((4 + g2) ^ (fr & 7)) << 3) + gh;
  const int vhi1 = (((6 + g2) ^ (fr & 7)) << 3) + gh;
  const int vlo2 = (((8 + g2) ^ (fr & 7)) << 3) + gh;
  const int vhi2 = (((10 + g2) ^ (fr & 7)) << 3) + gh;
  const int vlo3 = (((12 + g2) ^ (fr & 7)) << 3) + gh;
  const int vhi3 = (((14 + g2) ^ (fr & 7)) << 3) + gh;

#define STAGE(BI, N0)                                                       \
  { _Pragma("unroll") for (int q = 0; q < 4; ++q) {                         \
      gll16(kptr + (size_t)((N0) + q * 32 + srK) * HDIM + schK,             \
            &lK[BI][q * 2048 + wid * 512]);                                 \
      gll16(vptr + (size_t)(q * 16 + srV) * SEQ + (N0) + schV,              \
            &lV[BI][q * 2048 + wid * 512]);                                 \
    } }

#pragma unroll 1
  for (int pass = 0; pass < 2; ++pass) {
    const int qt = pass ? (124 - 4 * j + wid) : (4 * j + wid);
    const int q0 = qt * 16;
    const int nkt = pass ? (16 - (j >> 1)) : ((j >> 1) + 1);  // block-uniform
    const int qg = q0 + fr;  // this lane's q row

    const unsigned short* qb = Q + ((size_t)bh * SEQ + qg) * HDIM + g * 8;
    bf16x8 qa0 = *reinterpret_cast<const bf16x8*>(qb);        // d 0..31
    bf16x8 qa1 = *reinterpret_cast<const bf16x8*>(qb + 32);   // d 32..63

    f32x4 oacc[4];
#pragma unroll
    for (int i = 0; i < 4; ++i) oacc[i] = (f32x4){0.f, 0.f, 0.f, 0.f};
    float mreg = -3e30f;
    float lrow = 0.f;

    STAGE(0, 0);
    __syncthreads();

    for (int kt = 0; kt < nkt; ++kt) {
      const int bi = kt & 1;
      if (kt + 1 < nkt) STAGE(bi ^ 1, (kt + 1) * 128);
      const int n0 = kt * 128;
      // S' = K * Q^T over 8 key-subtiles: lane holds S'[key=cc*16+g*4+r][q=fr]
      f32x4 s[8];
#pragma unroll
      for (int cc = 0; cc < 8; ++cc) {
        bf16x8 kf0 = *reinterpret_cast<const bf16x8*>(
            &lK[bi][(cc * 16 + fr) * 64 + kswz0]);
        bf16x8 kf1 = *reinterpret_cast<const bf16x8*>(
            &lK[bi][(cc * 16 + fr) * 64 + kswz1]);
        s[cc] = (f32x4){0.f, 0.f, 0.f, 0.f};
        s[cc] = mfma16(kf0, qa0, s[cc]);
        s[cc] = mfma16(kf1, qa1, s[cc]);
      }
      // (last-tile-only) mask; per-lane max (log2 domain, Q pre-scaled)
      float sv[8][4];
      float lmax = -3e30f;
      if (kt == nkt - 1) {
#pragma unroll
        for (int cc = 0; cc < 8; ++cc)
#pragma unroll
          for (int r = 0; r < 4; ++r) {
            sv[cc][r] =
                (n0 + cc * 16 + g * 4 + r <= qg) ? s[cc][r] : -1e30f;
            lmax = fmaxf(lmax, sv[cc][r]);
          }
      } else {
#pragma unroll
        for (int cc = 0; cc < 8; ++cc)
#pragma unroll
          for (int r = 0; r < 4; ++r) {
            sv[cc][r] = s[cc][r];
            lmax = fmaxf(lmax, sv[cc][r]);
          }
      }
      // defer-max: scalar per-lane check; rescale reduces over g (2 shfl)
      if (!__all(lmax - mreg <= 11.5f)) {
        float tm = lmax;
        tm = fmaxf(tm, __shfl_xor(tm, 16, 64));
        tm = fmaxf(tm, __shfl_xor(tm, 32, 64));
        const float mn = fmaxf(mreg, tm);
        const float al = fexp2(mreg - mn);
        mreg = mn;
        lrow *= al;
#pragma unroll
        for (int nf = 0; nf < 4; ++nf) oacc[nf] *= al;
      }
      // P = 2^(sv - m), in-lane pack per 32-key blk (pi permutation)
      union { __bf16 e[8]; bf16x8 v; } pkA, pkB, pkC, pkD;
#pragma unroll
      for (int r = 0; r < 4; ++r) {
        float p0 = fexp2(sv[0][r] - mreg);
        float p1 = fexp2(sv[1][r] - mreg);
        float p2 = fexp2(sv[2][r] - mreg);
        float p3 = fexp2(sv[3][r] - mreg);
        float p4 = fexp2(sv[4][r] - mreg);
        float p5 = fexp2(sv[5][r] - mreg);
        float p6 = fexp2(sv[6][r] - mreg);
        float p7 = fexp2(sv[7][r] - mreg);
        lrow += ((p0 + p1) + (p2 + p3)) + ((p4 + p5) + (p6 + p7));
        pkA.e[r] = (__bf16)p0; pkA.e[4 + r] = (__bf16)p1;
        pkB.e[r] = (__bf16)p2; pkB.e[4 + r] = (__bf16)p3;
        pkC.e[r] = (__bf16)p4; pkC.e[4 + r] = (__bf16)p5;
        pkD.e[r] = (__bf16)p6; pkD.e[4 + r] = (__bf16)p7;
      }
      // O^T += V^T * P^T with pi-matched V fragments (2x b64 each)
#pragma unroll
      for (int nf = 0; nf < 4; ++nf) {
        const int vrow = (nf * 16 + fr) * 128;
        union { unsigned long long d[2]; bf16x8 v; } v0, v1, v2, v3;
        v0.d[0] = *reinterpret_cast<const unsigned long long*>(&lV[bi][vrow + vlo0]);
        v0.d[1] = *reinterpret_cast<const unsigned long long*>(&lV[bi][vrow + vhi0]);
        v1.d[0] = *reinterpret_cast<const unsigned long long*>(&lV[bi][vrow + vlo1]);
        v1.d[1] = *reinterpret_cast<const unsigned long long*>(&lV[bi][vrow + vhi1]);
        v2.d[0] = *reinterpret_cast<const unsigned long long*>(&lV[bi][vrow + vlo2]);
        v2.d[1] = *reinterpret_cast<const unsigned long long*>(&lV[bi][vrow + vhi2]);
        v3.d[0] = *reinterpret_cast<const unsigned long long*>(&lV[bi][vrow + vlo3]);
        v3.d[1] = *reinterpret_cast<const unsigned long long*>(&lV[bi][vrow + vhi3]);
        oacc[nf] = mfma16(v0.v, pkA.v, oacc[nf]);
        oacc[nf] = mfma16(v1.v, pkB.v, oacc[nf]);
        oacc[nf] = mfma16(v2.v, pkC.v, oacc[nf]);
        oacc[nf] = mfma16(v3.v, pkD.v, oacc[nf]);
      }
      __syncthreads();  // staged kt+1 complete; reads of buf bi done
    }

    // epilogue: lsum reduce over g (2 shfl); O^T -> O via direct stores
    float ls = lrow;
    ls += __shfl_xor(ls, 16, 64);
    ls += __shfl_xor(ls, 32, 64);
    const float inv = 1.f / ls;
    const size_t obase = ((size_t)b * SEQ + qg) * D_MODEL + h * HDIM + g * 4;
#pragma unroll
    for (int nf = 0; nf < 4; ++nf) {
      ushort4 o4;
      o4.x = f2bf(oacc[nf][0] * inv);
      o4.y = f2bf(oacc[nf][1] * inv);
      o4.z = f2bf(oacc[nf][2] * inv);
      o4.w = f2bf(oacc[nf][3] * inv);
      *reinterpret_cast<ushort4*>(&O[obase + nf * 16]) = o4;
    }
  }
#undef STAGE
}

extern "C" void kernel_launch(void* const* d_in, const int* in_sizes, int n_in,
                              void* d_out, int out_size, void* d_ws,
                              size_t ws_size, hipStream_t stream) {
  const float* x  = (const float*)d_in[0];
  const float* wq = (const float*)d_in[1];
  const float* bq = (const float*)d_in[2];
  const float* wk = (const float*)d_in[3];
  const float* bk = (const float*)d_in[4];
  const float* wv = (const float*)d_in[5];
  const float* bv = (const float*)d_in[6];
  const float* wo = (const float*)d_in[7];
  const float* bo = (const float*)d_in[8];
  float* out = (float*)d_out;

  char* w = (char*)d_ws;
  unsigned short* xb    = (unsigned short*)w; w += (size_t)MROWS * D_MODEL * 2;
  unsigned short* wqkvb = (unsigned short*)w; w += (size_t)3 * D_MODEL * D_MODEL * 2;
  unsigned short* wob   = (unsigned short*)w; w += (size_t)D_MODEL * D_MODEL * 2;
  unsigned short* Qb    = (unsigned short*)w; w += CHELEM * 2 * 3;  // Q,K,Vt
  unsigned short* Ob    = (unsigned short*)w; w += (size_t)MROWS * D_MODEL * 2;
  unsigned short* Kb  = Qb + CHELEM;
  unsigned short* Vtb = Qb + 2 * CHELEM;

  {
    int n4 = MROWS * D_MODEL / 4;
    cvt_f32_bf16<<<n4 / 256, 256, 0, stream>>>(x, xb, n4);
  }
  {
    int n4 = D_MODEL * D_MODEL / 4;  // 262144 -> 1024 blocks x 4
    cvt_w4<<<dim3(n4 / 256, 4), 256, 0, stream>>>(
        wq, wk, wv, wo, wqkvb, wqkvb + (size_t)D_MODEL * D_MODEL,
        wqkvb + (size_t)2 * D_MODEL * D_MODEL, wob);
  }

  // fused QKV projection: N = 3072
  gemm_bt2<3><<<dim3(3 * D_MODEL / 128, MROWS / 128), 256, 0, stream>>>(
      xb, wqkvb, bq, bk, bv, Qb, MROWS, 3 * D_MODEL, D_MODEL);

  attn_fwd14<<<512, 256, 0, stream>>>(Qb, Kb, Vtb, Ob);

  gemm_bt2<2><<<dim3(D_MODEL / 128, MROWS / 128), 256, 0, stream>>>(
      Ob, wob, bo, bo, bo, out, MROWS, D_MODEL, D_MODEL);
}

// Round 21
// 117.984 us; speedup vs baseline: 1.1562x; 1.0128x over previous
//
#include <hip/hip_runtime.h>
#include <hip/hip_bf16.h>

#define D_MODEL 1024
#define NHEADS  16
#define HDIM    64
#define SEQ     2048
#define BATCH   2
#define MROWS   (BATCH * SEQ)   // 4096
#define CHELEM  ((size_t)BATCH * NHEADS * SEQ * HDIM)  // 4194304

typedef __bf16 bf16x8 __attribute__((ext_vector_type(8)));
typedef float  f32x4  __attribute__((ext_vector_type(4)));

__device__ __forceinline__ unsigned short f2bf(float f) {
  unsigned u = __builtin_bit_cast(unsigned, f);
  return (unsigned short)((u + 0x7fffu + ((u >> 16) & 1u)) >> 16);
}

__device__ __forceinline__ float fexp2(float x) {
#if __has_builtin(__builtin_amdgcn_exp2f)
  return __builtin_amdgcn_exp2f(x);
#else
  return __expf(x * 0.6931471805599453f);
#endif
}

__device__ __forceinline__ f32x4 mfma16(bf16x8 a, bf16x8 b, f32x4 c) {
  return __builtin_amdgcn_mfma_f32_16x16x32_bf16(a, b, c, 0, 0, 0);
}

__device__ __forceinline__ void gll16(const unsigned short* g, unsigned short* l) {
  __builtin_amdgcn_global_load_lds(
      (const __attribute__((address_space(1))) unsigned*)g,
      (__attribute__((address_space(3))) unsigned*)l, 16, 0, 0);
}

__global__ void cvt_f32_bf16(const float* __restrict__ in,
                             unsigned short* __restrict__ out, int n4) {
  int i = blockIdx.x * blockDim.x + threadIdx.x;
  if (i >= n4) return;
  float4 v = reinterpret_cast<const float4*>(in)[i];
  ushort4 o;
  o.x = f2bf(v.x); o.y = f2bf(v.y); o.z = f2bf(v.z); o.w = f2bf(v.w);
  reinterpret_cast<ushort4*>(out)[i] = o;
}

// fused conversion of the 4 weight matrices (saves 3 launches)
__global__ void cvt_w4(const float* __restrict__ s0, const float* __restrict__ s1,
                       const float* __restrict__ s2, const float* __restrict__ s3,
                       unsigned short* __restrict__ d0, unsigned short* __restrict__ d1,
                       unsigned short* __restrict__ d2, unsigned short* __restrict__ d3) {
  int i = blockIdx.x * blockDim.x + threadIdx.x;  // n4 = D*D/4
  const int y = blockIdx.y;
  const float* s = (y == 0) ? s0 : (y == 1) ? s1 : (y == 2) ? s2 : s3;
  unsigned short* d = (y == 0) ? d0 : (y == 1) ? d1 : (y == 2) ? d2 : d3;
  float4 v = reinterpret_cast<const float4*>(s)[i];
  ushort4 o;
  o.x = f2bf(v.x); o.y = f2bf(v.y); o.z = f2bf(v.z); o.w = f2bf(v.w);
  reinterpret_cast<ushort4*>(d)[i] = o;
}

// ---------------- QKV GEMM: 8-wave 256x128 tile, BK=32 -------------------
// C = A[M,K] * Bt[N,K]^T + bias; N=3072; chunk 0->Q [B,H,S,64] (pre-scaled
// 0.125*log2e), 1->K [B,H,S,64], 2->V^T [B,H,64,S] (packed ushort4 stores).
// Staging: A = 2 gll16 calls (16 rows/wave each), B = 1; same 16B-chunk XOR
// swizzle as r16 (call bases == 0 mod 8 rows, so formulas carry over).
__global__ __launch_bounds__(512) void gemm_qkv(
    const unsigned short* __restrict__ A,
    const unsigned short* __restrict__ Bt,
    const float* __restrict__ b0, const float* __restrict__ b1,
    const float* __restrict__ b2,
    unsigned short* __restrict__ outp, int M, int N, int K) {
  __shared__ __align__(16) unsigned short lA[256 * 32];  // 16 KB
  __shared__ __align__(16) unsigned short lB[128 * 32];  // 8 KB
  const int tid = threadIdx.x;
  const int m0 = blockIdx.y * 256, n0 = blockIdx.x * 128;
  const int lane = tid & 63, wid = tid >> 6;   // wid 0..7
  const int wr = wid >> 1, wc = wid & 1;       // wr 0..3 (64-row bands)
  const int fr = lane & 15, g = lane >> 4;

  // staging: lane -> row (lane>>2) within a 16-row call, chunk lane&3,
  // source pre-swizzled by ((row>>1)&3) = ((lane>>3)&3)
  const int srow = lane >> 2;
  const int scol = ((lane & 3) ^ ((lane >> 3) & 3)) * 8;
  const unsigned short* gA0 = A + (size_t)(m0 + wid * 16 + srow) * K + scol;
  const unsigned short* gA1 =
      A + (size_t)(m0 + 128 + wid * 16 + srow) * K + scol;
  const unsigned short* gB = Bt + (size_t)(n0 + wid * 16 + srow) * K + scol;
  unsigned short* lAw0 = lA + wid * 16 * 32;
  unsigned short* lAw1 = lA + (128 + wid * 16) * 32;
  unsigned short* lBw = lB + wid * 16 * 32;

  const int rswz = (g ^ ((fr >> 1) & 3)) * 8;

  f32x4 acc[4][4];
#pragma unroll
  for (int i = 0; i < 4; ++i)
#pragma unroll
    for (int j = 0; j < 4; ++j) acc[i][j] = (f32x4){0.f, 0.f, 0.f, 0.f};

  for (int kt = 0; kt < K; kt += 32) {
    gll16(gA0 + kt, lAw0);
    gll16(gA1 + kt, lAw1);
    gll16(gB + kt, lBw);
    __syncthreads();
    bf16x8 af[4], bfv[4];
#pragma unroll
    for (int i = 0; i < 4; ++i)
      af[i] = *reinterpret_cast<const bf16x8*>(
          &lA[(wr * 64 + i * 16 + fr) * 32 + rswz]);
#pragma unroll
    for (int j = 0; j < 4; ++j)
      bfv[j] = *reinterpret_cast<const bf16x8*>(
          &lB[(wc * 64 + j * 16 + fr) * 32 + rswz]);
#pragma unroll
    for (int i = 0; i < 4; ++i)
#pragma unroll
      for (int j = 0; j < 4; ++j)
        acc[i][j] = mfma16(af[i], bfv[j], acc[i][j]);
    __syncthreads();
  }

  const int src = n0 >> 10;  // 0..2, uniform per block
  const float* bp = (src == 0) ? b0 : (src == 1 ? b1 : b2);
#pragma unroll
  for (int i = 0; i < 4; ++i)
#pragma unroll
    for (int j = 0; j < 4; ++j) {
      if (src == 2) {
        // V^T: 4 r-values consecutive in s -> one ushort4 store
        const int mb = m0 + wr * 64 + i * 16 + g * 4;
        const int n = n0 + wc * 64 + j * 16 + fr;
        const int within = n & 1023;
        const float bias = bp[within];
        const int b = mb >> 11, s0 = mb & 2047;
        const int hh = within >> 6, dh = within & 63;
        const size_t idx0 =
            ((size_t)(b * NHEADS + hh) * HDIM + dh) * SEQ + s0;
        ushort4 o4;
        o4.x = f2bf(acc[i][j][0] + bias);
        o4.y = f2bf(acc[i][j][1] + bias);
        o4.z = f2bf(acc[i][j][2] + bias);
        o4.w = f2bf(acc[i][j][3] + bias);
        *reinterpret_cast<ushort4*>(outp + 2 * CHELEM + idx0) = o4;
      } else {
#pragma unroll
        for (int r = 0; r < 4; ++r) {
          int m = m0 + wr * 64 + i * 16 + g * 4 + r;
          int n = n0 + wc * 64 + j * 16 + fr;
          int within = n & 1023;
          float val = acc[i][j][r] + bp[within];
          if (src == 0) val *= 0.1803368867f;  // 0.125 * log2(e)
          int b = m >> 11, s = m & 2047;
          int hh = within >> 6, dh = within & 63;
          size_t idx = ((size_t)(b * NHEADS + hh) * SEQ + s) * HDIM + dh;
          outp[(size_t)src * CHELEM + idx] = f2bf(val);
        }
      }
    }
}

// ---------------- Projection GEMM (r16-proven 128x128, 4-wave) ------------
__global__ __launch_bounds__(256) void gemm_proj(
    const unsigned short* __restrict__ A,
    const unsigned short* __restrict__ Bt,
    const float* __restrict__ b0,
    float* __restrict__ outp, int M, int N, int K) {
  __shared__ __align__(16) unsigned short lA[128 * 32];
  __shared__ __align__(16) unsigned short lB[128 * 32];
  const int tid = threadIdx.x;
  const int m0 = blockIdx.y * 128, n0 = blockIdx.x * 128;
  const int lane = tid & 63, wid = tid >> 6;
  const int wr = wid >> 1, wc = wid & 1;
  const int fr = lane & 15, g = lane >> 4;

  const int srow = wid * 32 + (lane >> 2);
  const int scol = ((lane & 3) ^ ((lane >> 3) & 3)) * 8;
  const unsigned short* gA = A + (size_t)(m0 + srow) * K + scol;
  const unsigned short* gB = Bt + (size_t)(n0 + srow) * K + scol;
  unsigned short* lAw = lA + wid * 1024;
  unsigned short* lBw = lB + wid * 1024;

  const int rswz = (g ^ ((fr >> 1) & 3)) * 8;

  f32x4 acc[4][4];
#pragma unroll
  for (int i = 0; i < 4; ++i)
#pragma unroll
    for (int j = 0; j < 4; ++j) acc[i][j] = (f32x4){0.f, 0.f, 0.f, 0.f};

  for (int kt = 0; kt < K; kt += 32) {
    gll16(gA + kt, lAw);
    gll16(gA + (size_t)16 * K + kt, lAw + 512);
    gll16(gB + kt, lBw);
    gll16(gB + (size_t)16 * K + kt, lBw + 512);
    __syncthreads();
    bf16x8 af[4], bfv[4];
#pragma unroll
    for (int i = 0; i < 4; ++i)
      af[i] = *reinterpret_cast<const bf16x8*>(
          &lA[(wr * 64 + i * 16 + fr) * 32 + rswz]);
#pragma unroll
    for (int j = 0; j < 4; ++j)
      bfv[j] = *reinterpret_cast<const bf16x8*>(
          &lB[(wc * 64 + j * 16 + fr) * 32 + rswz]);
#pragma unroll
    for (int i = 0; i < 4; ++i)
#pragma unroll
      for (int j = 0; j < 4; ++j)
        acc[i][j] = mfma16(af[i], bfv[j], acc[i][j]);
    __syncthreads();
  }

#pragma unroll
  for (int i = 0; i < 4; ++i)
#pragma unroll
    for (int j = 0; j < 4; ++j)
#pragma unroll
      for (int r = 0; r < 4; ++r) {
        int m = m0 + wr * 64 + i * 16 + g * 4 + r;
        int n = n0 + wc * 64 + j * 16 + fr;
        outp[(size_t)m * N + n] = acc[i][j][r] + b0[n];
      }
}

// Flash attention, swapped-operand, KVBLK=128 (r20-proven, verbatim).
// Q,K: [B,H,S,64] bf16 ; Vt: [B,H,64,S] bf16 ; O: [B,S,1024] bf16
__global__ __launch_bounds__(256) void attn_fwd14(
    const unsigned short* __restrict__ Q,
    const unsigned short* __restrict__ Km,
    const unsigned short* __restrict__ Vt,
    unsigned short* __restrict__ O) {
  const int tid = threadIdx.x;
  const int lane = tid & 63, wid = tid >> 6;
  const int fr = lane & 15, g = lane >> 4;
  const int lin = blockIdx.x;            // 0..511
  const int c = lin & 7;
  const int t = lin >> 3;                // 0..63
  const int j = t & 15;                  // block's pair index 0..15
  const int sgrp = t >> 4;               // 0..3
  const int slab = sgrp * 8 + c;         // 0..31
  const int b = slab >> 4, h = slab & 15;
  const int bh = b * NHEADS + h;

  __shared__ __align__(16) unsigned short lK[2][8192];   // 2 x 16KB
  __shared__ __align__(16) unsigned short lV[2][8192];   // 2 x 16KB

  const unsigned short* kptr = Km + (size_t)bh * SEQ * HDIM;
  const unsigned short* vptr = Vt + (size_t)bh * HDIM * SEQ;

  const int srK = tid >> 3;              // 0..31
  const int schK = (((tid & 7) ^ (srK & 7)) << 3);
  const int srV = tid >> 4;              // 0..15
  const int schV = (((tid & 15) ^ (srV & 7)) << 3);
  const int kswz0 = ((g ^ (fr & 7)) << 3);
  const int kswz1 = (((4 + g) ^ (fr & 7)) << 3);
  const int g2 = g >> 1, gh = (g & 1) * 4;
  const int vlo0 = (((0 + g2) ^ (fr & 7)) << 3) + gh;
  const int vhi0 = (((2 + g2) ^ (fr & 7)) << 3) + gh;
  const int vlo1 = (((4 + g2) ^ (fr & 7)) << 3) + gh;
  const int vhi1 = (((6 + g2) ^ (fr & 7)) << 3) + gh;
  const int vlo2 = (((8 + g2) ^ (fr & 7)) << 3) + gh;
  const int vhi2 = (((10 + g2) ^ (fr & 7)) << 3) + gh;
  const int vlo3 = (((12 + g2) ^ (fr & 7)) << 3) + gh;
  const int vhi3 = (((14 + g2) ^ (fr & 7)) << 3) + gh;

#define STAGE(BI, N0)                                                       \
  { _Pragma("unroll") for (int q = 0; q < 4; ++q) {                         \
      gll16(kptr + (size_t)((N0) + q * 32 + srK) * HDIM + schK,             \
            &lK[BI][q * 2048 + wid * 512]);                                 \
      gll16(vptr + (size_t)(q * 16 + srV) * SEQ + (N0) + schV,              \
            &lV[BI][q * 2048 + wid * 512]);                                 \
    } }

#pragma unroll 1
  for (int pass = 0; pass < 2; ++pass) {
    const int qt = pass ? (124 - 4 * j + wid) : (4 * j + wid);
    const int q0 = qt * 16;
    const int nkt = pass ? (16 - (j >> 1)) : ((j >> 1) + 1);
    const int qg = q0 + fr;

    const unsigned short* qb = Q + ((size_t)bh * SEQ + qg) * HDIM + g * 8;
    bf16x8 qa0 = *reinterpret_cast<const bf16x8*>(qb);
    bf16x8 qa1 = *reinterpret_cast<const bf16x8*>(qb + 32);

    f32x4 oacc[4];
#pragma unroll
    for (int i = 0; i < 4; ++i) oacc[i] = (f32x4){0.f, 0.f, 0.f, 0.f};
    float mreg = -3e30f;
    float lrow = 0.f;

    STAGE(0, 0);
    __syncthreads();

    for (int kt = 0; kt < nkt; ++kt) {
      const int bi = kt & 1;
      if (kt + 1 < nkt) STAGE(bi ^ 1, (kt + 1) * 128);
      const int n0 = kt * 128;
      f32x4 s[8];
#pragma unroll
      for (int cc = 0; cc < 8; ++cc) {
        bf16x8 kf0 = *reinterpret_cast<const bf16x8*>(
            &lK[bi][(cc * 16 + fr) * 64 + kswz0]);
        bf16x8 kf1 = *reinterpret_cast<const bf16x8*>(
            &lK[bi][(cc * 16 + fr) * 64 + kswz1]);
        s[cc] = (f32x4){0.f, 0.f, 0.f, 0.f};
        s[cc] = mfma16(kf0, qa0, s[cc]);
        s[cc] = mfma16(kf1, qa1, s[cc]);
      }
      float sv[8][4];
      float lmax = -3e30f;
      if (kt == nkt - 1) {
#pragma unroll
        for (int cc = 0; cc < 8; ++cc)
#pragma unroll
          for (int r = 0; r < 4; ++r) {
            sv[cc][r] =
                (n0 + cc * 16 + g * 4 + r <= qg) ? s[cc][r] : -1e30f;
            lmax = fmaxf(lmax, sv[cc][r]);
          }
      } else {
#pragma unroll
        for (int cc = 0; cc < 8; ++cc)
#pragma unroll
          for (int r = 0; r < 4; ++r) {
            sv[cc][r] = s[cc][r];
            lmax = fmaxf(lmax, sv[cc][r]);
          }
      }
      if (!__all(lmax - mreg <= 11.5f)) {
        float tm = lmax;
        tm = fmaxf(tm, __shfl_xor(tm, 16, 64));
        tm = fmaxf(tm, __shfl_xor(tm, 32, 64));
        const float mn = fmaxf(mreg, tm);
        const float al = fexp2(mreg - mn);
        mreg = mn;
        lrow *= al;
#pragma unroll
        for (int nf = 0; nf < 4; ++nf) oacc[nf] *= al;
      }
      union { __bf16 e[8]; bf16x8 v; } pkA, pkB, pkC, pkD;
#pragma unroll
      for (int r = 0; r < 4; ++r) {
        float p0 = fexp2(sv[0][r] - mreg);
        float p1 = fexp2(sv[1][r] - mreg);
        float p2 = fexp2(sv[2][r] - mreg);
        float p3 = fexp2(sv[3][r] - mreg);
        float p4 = fexp2(sv[4][r] - mreg);
        float p5 = fexp2(sv[5][r] - mreg);
        float p6 = fexp2(sv[6][r] - mreg);
        float p7 = fexp2(sv[7][r] - mreg);
        lrow += ((p0 + p1) + (p2 + p3)) + ((p4 + p5) + (p6 + p7));
        pkA.e[r] = (__bf16)p0; pkA.e[4 + r] = (__bf16)p1;
        pkB.e[r] = (__bf16)p2; pkB.e[4 + r] = (__bf16)p3;
        pkC.e[r] = (__bf16)p4; pkC.e[4 + r] = (__bf16)p5;
        pkD.e[r] = (__bf16)p6; pkD.e[4 + r] = (__bf16)p7;
      }
#pragma unroll
      for (int nf = 0; nf < 4; ++nf) {
        const int vrow = (nf * 16 + fr) * 128;
        union { unsigned long long d[2]; bf16x8 v; } v0, v1, v2, v3;
        v0.d[0] = *reinterpret_cast<const unsigned long long*>(&lV[bi][vrow + vlo0]);
        v0.d[1] = *reinterpret_cast<const unsigned long long*>(&lV[bi][vrow + vhi0]);
        v1.d[0] = *reinterpret_cast<const unsigned long long*>(&lV[bi][vrow + vlo1]);
        v1.d[1] = *reinterpret_cast<const unsigned long long*>(&lV[bi][vrow + vhi1]);
        v2.d[0] = *reinterpret_cast<const unsigned long long*>(&lV[bi][vrow + vlo2]);
        v2.d[1] = *reinterpret_cast<const unsigned long long*>(&lV[bi][vrow + vhi2]);
        v3.d[0] = *reinterpret_cast<const unsigned long long*>(&lV[bi][vrow + vlo3]);
        v3.d[1] = *reinterpret_cast<const unsigned long long*>(&lV[bi][vrow + vhi3]);
        oacc[nf] = mfma16(v0.v, pkA.v, oacc[nf]);
        oacc[nf] = mfma16(v1.v, pkB.v, oacc[nf]);
        oacc[nf] = mfma16(v2.v, pkC.v, oacc[nf]);
        oacc[nf] = mfma16(v3.v, pkD.v, oacc[nf]);
      }
      __syncthreads();
    }

    float ls = lrow;
    ls += __shfl_xor(ls, 16, 64);
    ls += __shfl_xor(ls, 32, 64);
    const float inv = 1.f / ls;
    const size_t obase = ((size_t)b * SEQ + qg) * D_MODEL + h * HDIM + g * 4;
#pragma unroll
    for (int nf = 0; nf < 4; ++nf) {
      ushort4 o4;
      o4.x = f2bf(oacc[nf][0] * inv);
      o4.y = f2bf(oacc[nf][1] * inv);
      o4.z = f2bf(oacc[nf][2] * inv);
      o4.w = f2bf(oacc[nf][3] * inv);
      *reinterpret_cast<ushort4*>(&O[obase + nf * 16]) = o4;
    }
  }
#undef STAGE
}

extern "C" void kernel_launch(void* const* d_in, const int* in_sizes, int n_in,
                              void* d_out, int out_size, void* d_ws,
                              size_t ws_size, hipStream_t stream) {
  const float* x  = (const float*)d_in[0];
  const float* wq = (const float*)d_in[1];
  const float* bq = (const float*)d_in[2];
  const float* wk = (const float*)d_in[3];
  const float* bk = (const float*)d_in[4];
  const float* wv = (const float*)d_in[5];
  const float* bv = (const float*)d_in[6];
  const float* wo = (const float*)d_in[7];
  const float* bo = (const float*)d_in[8];
  float* out = (float*)d_out;

  char* w = (char*)d_ws;
  unsigned short* xb    = (unsigned short*)w; w += (size_t)MROWS * D_MODEL * 2;
  unsigned short* wqkvb = (unsigned short*)w; w += (size_t)3 * D_MODEL * D_MODEL * 2;
  unsigned short* wob   = (unsigned short*)w; w += (size_t)D_MODEL * D_MODEL * 2;
  unsigned short* Qb    = (unsigned short*)w; w += CHELEM * 2 * 3;  // Q,K,Vt
  unsigned short* Ob    = (unsigned short*)w; w += (size_t)MROWS * D_MODEL * 2;
  unsigned short* Kb  = Qb + CHELEM;
  unsigned short* Vtb = Qb + 2 * CHELEM;

  {
    int n4 = MROWS * D_MODEL / 4;
    cvt_f32_bf16<<<n4 / 256, 256, 0, stream>>>(x, xb, n4);
  }
  {
    int n4 = D_MODEL * D_MODEL / 4;  // 262144 -> 1024 blocks x 4
    cvt_w4<<<dim3(n4 / 256, 4), 256, 0, stream>>>(
        wq, wk, wv, wo, wqkvb, wqkvb + (size_t)D_MODEL * D_MODEL,
        wqkvb + (size_t)2 * D_MODEL * D_MODEL, wob);
  }

  // fused QKV projection: N = 3072, 8-wave 256x128 tiles
  gemm_qkv<<<dim3(3 * D_MODEL / 128, MROWS / 256), 512, 0, stream>>>(
      xb, wqkvb, bq, bk, bv, Qb, MROWS, 3 * D_MODEL, D_MODEL);

  attn_fwd14<<<512, 256, 0, stream>>>(Qb, Kb, Vtb, Ob);

  gemm_proj<<<dim3(D_MODEL / 128, MROWS / 128), 256, 0, stream>>>(
      Ob, wob, bo, out, MROWS, D_MODEL, D_MODEL);
}

// Round 22
// 111.752 us; speedup vs baseline: 1.2207x; 1.0558x over previous
//
#include <hip/hip_runtime.h>
#include <hip/hip_bf16.h>

#define D_MODEL 1024
#define NHEADS  16
#define HDIM    64
#define SEQ     2048
#define BATCH   2
#define MROWS   (BATCH * SEQ)   // 4096
#define CHELEM  ((size_t)BATCH * NHEADS * SEQ * HDIM)  // 4194304

typedef __bf16 bf16x8 __attribute__((ext_vector_type(8)));
typedef float  f32x4  __attribute__((ext_vector_type(4)));

__device__ __forceinline__ unsigned short f2bf(float f) {
  unsigned u = __builtin_bit_cast(unsigned, f);
  return (unsigned short)((u + 0x7fffu + ((u >> 16) & 1u)) >> 16);
}

__device__ __forceinline__ float fexp2(float x) {
#if __has_builtin(__builtin_amdgcn_exp2f)
  return __builtin_amdgcn_exp2f(x);
#else
  return __expf(x * 0.6931471805599453f);
#endif
}

__device__ __forceinline__ f32x4 mfma16(bf16x8 a, bf16x8 b, f32x4 c) {
  return __builtin_amdgcn_mfma_f32_16x16x32_bf16(a, b, c, 0, 0, 0);
}

__device__ __forceinline__ void gll16(const unsigned short* g, unsigned short* l) {
  __builtin_amdgcn_global_load_lds(
      (const __attribute__((address_space(1))) unsigned*)g,
      (__attribute__((address_space(3))) unsigned*)l, 16, 0, 0);
}

// single fused f32->bf16 conversion: y 0..3 = {wq,wk,wv,wo}, y 4..7 = x
// quarters (each slice is exactly D*D/4 = 262144 float4s).
__global__ void cvt_all(const float* __restrict__ x,
                        const float* __restrict__ wq, const float* __restrict__ wk,
                        const float* __restrict__ wv, const float* __restrict__ wo,
                        unsigned short* __restrict__ xb,
                        unsigned short* __restrict__ wqkvb,
                        unsigned short* __restrict__ wob) {
  const int i = blockIdx.x * blockDim.x + threadIdx.x;  // 0..262143
  const int y = blockIdx.y;                             // 0..7
  const float* s;
  unsigned short* d;
  if (y < 4) {
    s = (y == 0) ? wq : (y == 1) ? wk : (y == 2) ? wv : wo;
    d = (y == 3) ? wob : wqkvb + (size_t)y * D_MODEL * D_MODEL;
  } else {
    s = x + (size_t)(y - 4) * 262144 * 4;
    d = xb + (size_t)(y - 4) * 262144 * 4;
  }
  float4 v = reinterpret_cast<const float4*>(s)[i];
  ushort4 o;
  o.x = f2bf(v.x); o.y = f2bf(v.y); o.z = f2bf(v.z); o.w = f2bf(v.w);
  reinterpret_cast<ushort4*>(d)[i] = o;
}

// ---------------- QKV GEMM: 8-wave 256x128 tile, BK=32 (r21-proven) ------
__global__ __launch_bounds__(512) void gemm_qkv(
    const unsigned short* __restrict__ A,
    const unsigned short* __restrict__ Bt,
    const float* __restrict__ b0, const float* __restrict__ b1,
    const float* __restrict__ b2,
    unsigned short* __restrict__ outp, int M, int N, int K) {
  __shared__ __align__(16) unsigned short lA[256 * 32];  // 16 KB
  __shared__ __align__(16) unsigned short lB[128 * 32];  // 8 KB
  const int tid = threadIdx.x;
  const int m0 = blockIdx.y * 256, n0 = blockIdx.x * 128;
  const int lane = tid & 63, wid = tid >> 6;   // wid 0..7
  const int wr = wid >> 1, wc = wid & 1;       // wr 0..3 (64-row bands)
  const int fr = lane & 15, g = lane >> 4;

  const int srow = lane >> 2;
  const int scol = ((lane & 3) ^ ((lane >> 3) & 3)) * 8;
  const unsigned short* gA0 = A + (size_t)(m0 + wid * 16 + srow) * K + scol;
  const unsigned short* gA1 =
      A + (size_t)(m0 + 128 + wid * 16 + srow) * K + scol;
  const unsigned short* gB = Bt + (size_t)(n0 + wid * 16 + srow) * K + scol;
  unsigned short* lAw0 = lA + wid * 16 * 32;
  unsigned short* lAw1 = lA + (128 + wid * 16) * 32;
  unsigned short* lBw = lB + wid * 16 * 32;

  const int rswz = (g ^ ((fr >> 1) & 3)) * 8;

  f32x4 acc[4][4];
#pragma unroll
  for (int i = 0; i < 4; ++i)
#pragma unroll
    for (int j = 0; j < 4; ++j) acc[i][j] = (f32x4){0.f, 0.f, 0.f, 0.f};

  for (int kt = 0; kt < K; kt += 32) {
    gll16(gA0 + kt, lAw0);
    gll16(gA1 + kt, lAw1);
    gll16(gB + kt, lBw);
    __syncthreads();
    bf16x8 af[4], bfv[4];
#pragma unroll
    for (int i = 0; i < 4; ++i)
      af[i] = *reinterpret_cast<const bf16x8*>(
          &lA[(wr * 64 + i * 16 + fr) * 32 + rswz]);
#pragma unroll
    for (int j = 0; j < 4; ++j)
      bfv[j] = *reinterpret_cast<const bf16x8*>(
          &lB[(wc * 64 + j * 16 + fr) * 32 + rswz]);
#pragma unroll
    for (int i = 0; i < 4; ++i)
#pragma unroll
      for (int j = 0; j < 4; ++j)
        acc[i][j] = mfma16(af[i], bfv[j], acc[i][j]);
    __syncthreads();
  }

  const int src = n0 >> 10;  // 0..2, uniform per block
  const float* bp = (src == 0) ? b0 : (src == 1 ? b1 : b2);
#pragma unroll
  for (int i = 0; i < 4; ++i)
#pragma unroll
    for (int j = 0; j < 4; ++j) {
      if (src == 2) {
        const int mb = m0 + wr * 64 + i * 16 + g * 4;
        const int n = n0 + wc * 64 + j * 16 + fr;
        const int within = n & 1023;
        const float bias = bp[within];
        const int b = mb >> 11, s0 = mb & 2047;
        const int hh = within >> 6, dh = within & 63;
        const size_t idx0 =
            ((size_t)(b * NHEADS + hh) * HDIM + dh) * SEQ + s0;
        ushort4 o4;
        o4.x = f2bf(acc[i][j][0] + bias);
        o4.y = f2bf(acc[i][j][1] + bias);
        o4.z = f2bf(acc[i][j][2] + bias);
        o4.w = f2bf(acc[i][j][3] + bias);
        *reinterpret_cast<ushort4*>(outp + 2 * CHELEM + idx0) = o4;
      } else {
#pragma unroll
        for (int r = 0; r < 4; ++r) {
          int m = m0 + wr * 64 + i * 16 + g * 4 + r;
          int n = n0 + wc * 64 + j * 16 + fr;
          int within = n & 1023;
          float val = acc[i][j][r] + bp[within];
          if (src == 0) val *= 0.1803368867f;  // 0.125 * log2(e)
          int b = m >> 11, s = m & 2047;
          int hh = within >> 6, dh = within & 63;
          size_t idx = ((size_t)(b * NHEADS + hh) * SEQ + s) * HDIM + dh;
          outp[(size_t)src * CHELEM + idx] = f2bf(val);
        }
      }
    }
}

// ---------------- Projection GEMM: 64x128 tile, 4 waves, 2048 waves -------
// per-wave output 64x32 (acc[4][2]); grid (8,64)=512 blocks -> 2 waves/SIMD
// (old 128x128 config was 1 wave/SIMD, pure latency starvation).
__global__ __launch_bounds__(256) void gemm_proj(
    const unsigned short* __restrict__ A,
    const unsigned short* __restrict__ Bt,
    const float* __restrict__ b0,
    float* __restrict__ outp, int M, int N, int K) {
  __shared__ __align__(16) unsigned short lA[64 * 32];   // 4 KB
  __shared__ __align__(16) unsigned short lB[128 * 32];  // 8 KB
  const int tid = threadIdx.x;
  const int m0 = blockIdx.y * 64, n0 = blockIdx.x * 128;
  const int lane = tid & 63, wid = tid >> 6;
  const int fr = lane & 15, g = lane >> 4;

  // staging: wave wid covers A rows [wid*16,+16), B rows [wid*16,+16) and
  // [64+wid*16,+16); all call bases == 0 mod 8 -> r16 swizzle formulas hold
  const int srow = lane >> 2;
  const int scol = ((lane & 3) ^ ((lane >> 3) & 3)) * 8;
  const unsigned short* gA = A + (size_t)(m0 + wid * 16 + srow) * K + scol;
  const unsigned short* gB0 = Bt + (size_t)(n0 + wid * 16 + srow) * K + scol;
  const unsigned short* gB1 = gB0 + (size_t)64 * K;
  unsigned short* lAw = lA + wid * 512;
  unsigned short* lBw0 = lB + wid * 512;
  unsigned short* lBw1 = lB + 2048 + wid * 512;

  const int rswz = (g ^ ((fr >> 1) & 3)) * 8;

  f32x4 acc[4][2];
#pragma unroll
  for (int i = 0; i < 4; ++i)
#pragma unroll
    for (int j = 0; j < 2; ++j) acc[i][j] = (f32x4){0.f, 0.f, 0.f, 0.f};

  for (int kt = 0; kt < K; kt += 32) {
    gll16(gA + kt, lAw);
    gll16(gB0 + kt, lBw0);
    gll16(gB1 + kt, lBw1);
    __syncthreads();
    bf16x8 af[4], bfv[2];
#pragma unroll
    for (int i = 0; i < 4; ++i)
      af[i] = *reinterpret_cast<const bf16x8*>(
          &lA[(i * 16 + fr) * 32 + rswz]);
#pragma unroll
    for (int j = 0; j < 2; ++j)
      bfv[j] = *reinterpret_cast<const bf16x8*>(
          &lB[(wid * 32 + j * 16 + fr) * 32 + rswz]);
#pragma unroll
    for (int i = 0; i < 4; ++i)
#pragma unroll
      for (int j = 0; j < 2; ++j)
        acc[i][j] = mfma16(af[i], bfv[j], acc[i][j]);
    __syncthreads();
  }

#pragma unroll
  for (int i = 0; i < 4; ++i)
#pragma unroll
    for (int j = 0; j < 2; ++j)
#pragma unroll
      for (int r = 0; r < 4; ++r) {
        int m = m0 + i * 16 + g * 4 + r;
        int n = n0 + wid * 32 + j * 16 + fr;
        outp[(size_t)m * N + n] = acc[i][j][r] + b0[n];
      }
}

// Flash attention, swapped-operand, KVBLK=128 (r20-proven, verbatim).
// Q,K: [B,H,S,64] bf16 ; Vt: [B,H,64,S] bf16 ; O: [B,S,1024] bf16
__global__ __launch_bounds__(256) void attn_fwd14(
    const unsigned short* __restrict__ Q,
    const unsigned short* __restrict__ Km,
    const unsigned short* __restrict__ Vt,
    unsigned short* __restrict__ O) {
  const int tid = threadIdx.x;
  const int lane = tid & 63, wid = tid >> 6;
  const int fr = lane & 15, g = lane >> 4;
  const int lin = blockIdx.x;            // 0..511
  const int c = lin & 7;
  const int t = lin >> 3;                // 0..63
  const int j = t & 15;                  // block's pair index 0..15
  const int sgrp = t >> 4;               // 0..3
  const int slab = sgrp * 8 + c;         // 0..31
  const int b = slab >> 4, h = slab & 15;
  const int bh = b * NHEADS + h;

  __shared__ __align__(16) unsigned short lK[2][8192];   // 2 x 16KB
  __shared__ __align__(16) unsigned short lV[2][8192];   // 2 x 16KB

  const unsigned short* kptr = Km + (size_t)bh * SEQ * HDIM;
  const unsigned short* vptr = Vt + (size_t)bh * HDIM * SEQ;

  const int srK = tid >> 3;              // 0..31
  const int schK = (((tid & 7) ^ (srK & 7)) << 3);
  const int srV = tid >> 4;              // 0..15
  const int schV = (((tid & 15) ^ (srV & 7)) << 3);
  const int kswz0 = ((g ^ (fr & 7)) << 3);
  const int kswz1 = (((4 + g) ^ (fr & 7)) << 3);
  const int g2 = g >> 1, gh = (g & 1) * 4;
  const int vlo0 = (((0 + g2) ^ (fr & 7)) << 3) + gh;
  const int vhi0 = (((2 + g2) ^ (fr & 7)) << 3) + gh;
  const int vlo1 = (((4 + g2) ^ (fr & 7)) << 3) + gh;
  const int vhi1 = (((6 + g2) ^ (fr & 7)) << 3) + gh;
  const int vlo2 = (((8 + g2) ^ (fr & 7)) << 3) + gh;
  const int vhi2 = (((10 + g2) ^ (fr & 7)) << 3) + gh;
  const int vlo3 = (((12 + g2) ^ (fr & 7)) << 3) + gh;
  const int vhi3 = (((14 + g2) ^ (fr & 7)) << 3) + gh;

#define STAGE(BI, N0)                                                       \
  { _Pragma("unroll") for (int q = 0; q < 4; ++q) {                         \
      gll16(kptr + (size_t)((N0) + q * 32 + srK) * HDIM + schK,             \
            &lK[BI][q * 2048 + wid * 512]);                                 \
      gll16(vptr + (size_t)(q * 16 + srV) * SEQ + (N0) + schV,              \
            &lV[BI][q * 2048 + wid * 512]);                                 \
    } }

#pragma unroll 1
  for (int pass = 0; pass < 2; ++pass) {
    const int qt = pass ? (124 - 4 * j + wid) : (4 * j + wid);
    const int q0 = qt * 16;
    const int nkt = pass ? (16 - (j >> 1)) : ((j >> 1) + 1);
    const int qg = q0 + fr;

    const unsigned short* qb = Q + ((size_t)bh * SEQ + qg) * HDIM + g * 8;
    bf16x8 qa0 = *reinterpret_cast<const bf16x8*>(qb);
    bf16x8 qa1 = *reinterpret_cast<const bf16x8*>(qb + 32);

    f32x4 oacc[4];
#pragma unroll
    for (int i = 0; i < 4; ++i) oacc[i] = (f32x4){0.f, 0.f, 0.f, 0.f};
    float mreg = -3e30f;
    float lrow = 0.f;

    STAGE(0, 0);
    __syncthreads();

    for (int kt = 0; kt < nkt; ++kt) {
      const int bi = kt & 1;
      if (kt + 1 < nkt) STAGE(bi ^ 1, (kt + 1) * 128);
      const int n0 = kt * 128;
      f32x4 s[8];
#pragma unroll
      for (int cc = 0; cc < 8; ++cc) {
        bf16x8 kf0 = *reinterpret_cast<const bf16x8*>(
            &lK[bi][(cc * 16 + fr) * 64 + kswz0]);
        bf16x8 kf1 = *reinterpret_cast<const bf16x8*>(
            &lK[bi][(cc * 16 + fr) * 64 + kswz1]);
        s[cc] = (f32x4){0.f, 0.f, 0.f, 0.f};
        s[cc] = mfma16(kf0, qa0, s[cc]);
        s[cc] = mfma16(kf1, qa1, s[cc]);
      }
      float sv[8][4];
      float lmax = -3e30f;
      if (kt == nkt - 1) {
#pragma unroll
        for (int cc = 0; cc < 8; ++cc)
#pragma unroll
          for (int r = 0; r < 4; ++r) {
            sv[cc][r] =
                (n0 + cc * 16 + g * 4 + r <= qg) ? s[cc][r] : -1e30f;
            lmax = fmaxf(lmax, sv[cc][r]);
          }
      } else {
#pragma unroll
        for (int cc = 0; cc < 8; ++cc)
#pragma unroll
          for (int r = 0; r < 4; ++r) {
            sv[cc][r] = s[cc][r];
            lmax = fmaxf(lmax, sv[cc][r]);
          }
      }
      if (!__all(lmax - mreg <= 11.5f)) {
        float tm = lmax;
        tm = fmaxf(tm, __shfl_xor(tm, 16, 64));
        tm = fmaxf(tm, __shfl_xor(tm, 32, 64));
        const float mn = fmaxf(mreg, tm);
        const float al = fexp2(mreg - mn);
        mreg = mn;
        lrow *= al;
#pragma unroll
        for (int nf = 0; nf < 4; ++nf) oacc[nf] *= al;
      }
      union { __bf16 e[8]; bf16x8 v; } pkA, pkB, pkC, pkD;
#pragma unroll
      for (int r = 0; r < 4; ++r) {
        float p0 = fexp2(sv[0][r] - mreg);
        float p1 = fexp2(sv[1][r] - mreg);
        float p2 = fexp2(sv[2][r] - mreg);
        float p3 = fexp2(sv[3][r] - mreg);
        float p4 = fexp2(sv[4][r] - mreg);
        float p5 = fexp2(sv[5][r] - mreg);
        float p6 = fexp2(sv[6][r] - mreg);
        float p7 = fexp2(sv[7][r] - mreg);
        lrow += ((p0 + p1) + (p2 + p3)) + ((p4 + p5) + (p6 + p7));
        pkA.e[r] = (__bf16)p0; pkA.e[4 + r] = (__bf16)p1;
        pkB.e[r] = (__bf16)p2; pkB.e[4 + r] = (__bf16)p3;
        pkC.e[r] = (__bf16)p4; pkC.e[4 + r] = (__bf16)p5;
        pkD.e[r] = (__bf16)p6; pkD.e[4 + r] = (__bf16)p7;
      }
#pragma unroll
      for (int nf = 0; nf < 4; ++nf) {
        const int vrow = (nf * 16 + fr) * 128;
        union { unsigned long long d[2]; bf16x8 v; } v0, v1, v2, v3;
        v0.d[0] = *reinterpret_cast<const unsigned long long*>(&lV[bi][vrow + vlo0]);
        v0.d[1] = *reinterpret_cast<const unsigned long long*>(&lV[bi][vrow + vhi0]);
        v1.d[0] = *reinterpret_cast<const unsigned long long*>(&lV[bi][vrow + vlo1]);
        v1.d[1] = *reinterpret_cast<const unsigned long long*>(&lV[bi][vrow + vhi1]);
        v2.d[0] = *reinterpret_cast<const unsigned long long*>(&lV[bi][vrow + vlo2]);
        v2.d[1] = *reinterpret_cast<const unsigned long long*>(&lV[bi][vrow + vhi2]);
        v3.d[0] = *reinterpret_cast<const unsigned long long*>(&lV[bi][vrow + vlo3]);
        v3.d[1] = *reinterpret_cast<const unsigned long long*>(&lV[bi][vrow + vhi3]);
        oacc[nf] = mfma16(v0.v, pkA.v, oacc[nf]);
        oacc[nf] = mfma16(v1.v, pkB.v, oacc[nf]);
        oacc[nf] = mfma16(v2.v, pkC.v, oacc[nf]);
        oacc[nf] = mfma16(v3.v, pkD.v, oacc[nf]);
      }
      __syncthreads();
    }

    float ls = lrow;
    ls += __shfl_xor(ls, 16, 64);
    ls += __shfl_xor(ls, 32, 64);
    const float inv = 1.f / ls;
    const size_t obase = ((size_t)b * SEQ + qg) * D_MODEL + h * HDIM + g * 4;
#pragma unroll
    for (int nf = 0; nf < 4; ++nf) {
      ushort4 o4;
      o4.x = f2bf(oacc[nf][0] * inv);
      o4.y = f2bf(oacc[nf][1] * inv);
      o4.z = f2bf(oacc[nf][2] * inv);
      o4.w = f2bf(oacc[nf][3] * inv);
      *reinterpret_cast<ushort4*>(&O[obase + nf * 16]) = o4;
    }
  }
#undef STAGE
}

extern "C" void kernel_launch(void* const* d_in, const int* in_sizes, int n_in,
                              void* d_out, int out_size, void* d_ws,
                              size_t ws_size, hipStream_t stream) {
  const float* x  = (const float*)d_in[0];
  const float* wq = (const float*)d_in[1];
  const float* bq = (const float*)d_in[2];
  const float* wk = (const float*)d_in[3];
  const float* bk = (const float*)d_in[4];
  const float* wv = (const float*)d_in[5];
  const float* bv = (const float*)d_in[6];
  const float* wo = (const float*)d_in[7];
  const float* bo = (const float*)d_in[8];
  float* out = (float*)d_out;

  char* w = (char*)d_ws;
  unsigned short* xb    = (unsigned short*)w; w += (size_t)MROWS * D_MODEL * 2;
  unsigned short* wqkvb = (unsigned short*)w; w += (size_t)3 * D_MODEL * D_MODEL * 2;
  unsigned short* wob   = (unsigned short*)w; w += (size_t)D_MODEL * D_MODEL * 2;
  unsigned short* Qb    = (unsigned short*)w; w += CHELEM * 2 * 3;  // Q,K,Vt
  unsigned short* Ob    = (unsigned short*)w; w += (size_t)MROWS * D_MODEL * 2;
  unsigned short* Kb  = Qb + CHELEM;
  unsigned short* Vtb = Qb + 2 * CHELEM;

  // single fused conversion pass: weights + x (8 equal slices)
  cvt_all<<<dim3(1024, 8), 256, 0, stream>>>(x, wq, wk, wv, wo, xb, wqkvb, wob);

  // fused QKV projection: N = 3072, 8-wave 256x128 tiles
  gemm_qkv<<<dim3(3 * D_MODEL / 128, MROWS / 256), 512, 0, stream>>>(
      xb, wqkvb, bq, bk, bv, Qb, MROWS, 3 * D_MODEL, D_MODEL);

  attn_fwd14<<<512, 256, 0, stream>>>(Qb, Kb, Vtb, Ob);

  // output projection: 64x128 tiles, 2048 waves (2/SIMD)
  gemm_proj<<<dim3(D_MODEL / 128, MROWS / 64), 256, 0, stream>>>(
      Ob, wob, bo, out, MROWS, D_MODEL, D_MODEL);
}

// Round 23
// 107.821 us; speedup vs baseline: 1.2652x; 1.0365x over previous
//
#include <hip/hip_runtime.h>
#include <hip/hip_bf16.h>

#define D_MODEL 1024
#define NHEADS  16
#define HDIM    64
#define SEQ     2048
#define BATCH   2
#define MROWS   (BATCH * SEQ)   // 4096
#define CHELEM  ((size_t)BATCH * NHEADS * SEQ * HDIM)  // 4194304

typedef __bf16 bf16x8 __attribute__((ext_vector_type(8)));
typedef float  f32x4  __attribute__((ext_vector_type(4)));

__device__ __forceinline__ unsigned short f2bf(float f) {
  unsigned u = __builtin_bit_cast(unsigned, f);
  return (unsigned short)((u + 0x7fffu + ((u >> 16) & 1u)) >> 16);
}

__device__ __forceinline__ float fexp2(float x) {
#if __has_builtin(__builtin_amdgcn_exp2f)
  return __builtin_amdgcn_exp2f(x);
#else
  return __expf(x * 0.6931471805599453f);
#endif
}

__device__ __forceinline__ f32x4 mfma16(bf16x8 a, bf16x8 b, f32x4 c) {
  return __builtin_amdgcn_mfma_f32_16x16x32_bf16(a, b, c, 0, 0, 0);
}

__device__ __forceinline__ void gll16(const unsigned short* g, unsigned short* l) {
  __builtin_amdgcn_global_load_lds(
      (const __attribute__((address_space(1))) unsigned*)g,
      (__attribute__((address_space(3))) unsigned*)l, 16, 0, 0);
}

// single fused f32->bf16 conversion: y 0..3 = {wq,wk,wv,wo}, y 4..7 = x
// quarters (each slice is exactly D*D/4 = 262144 float4s).
__global__ void cvt_all(const float* __restrict__ x,
                        const float* __restrict__ wq, const float* __restrict__ wk,
                        const float* __restrict__ wv, const float* __restrict__ wo,
                        unsigned short* __restrict__ xb,
                        unsigned short* __restrict__ wqkvb,
                        unsigned short* __restrict__ wob) {
  const int i = blockIdx.x * blockDim.x + threadIdx.x;  // 0..262143
  const int y = blockIdx.y;                             // 0..7
  const float* s;
  unsigned short* d;
  if (y < 4) {
    s = (y == 0) ? wq : (y == 1) ? wk : (y == 2) ? wv : wo;
    d = (y == 3) ? wob : wqkvb + (size_t)y * D_MODEL * D_MODEL;
  } else {
    s = x + (size_t)(y - 4) * 262144 * 4;
    d = xb + (size_t)(y - 4) * 262144 * 4;
  }
  float4 v = reinterpret_cast<const float4*>(s)[i];
  ushort4 o;
  o.x = f2bf(v.x); o.y = f2bf(v.y); o.z = f2bf(v.z); o.w = f2bf(v.w);
  reinterpret_cast<ushort4*>(d)[i] = o;
}

// ---------------- QKV GEMM: 8-wave 256x128 tile, BK=32 (r21-proven) ------
// Grid: 1-D 384 with XCD swizzle (lin&7 = XCD, 48 contiguous work-items per
// XCD = 2 m-panels x all 24 n-blocks -> A panel + B L2-resident per XCD).
__global__ __launch_bounds__(512) void gemm_qkv(
    const unsigned short* __restrict__ A,
    const unsigned short* __restrict__ Bt,
    const float* __restrict__ b0, const float* __restrict__ b1,
    const float* __restrict__ b2,
    unsigned short* __restrict__ outp, int M, int N, int K) {
  __shared__ __align__(16) unsigned short lA[256 * 32];  // 16 KB
  __shared__ __align__(16) unsigned short lB[128 * 32];  // 8 KB
  const int tid = threadIdx.x;
  // XCD-aware decode: 384 blocks, 48 per XCD covering all n for 2 m rows
  const int lin = blockIdx.x;
  const int c2 = (lin & 7) * 48 + (lin >> 3);  // 0..383, XCD-chunked
  const int m0 = (c2 / 24) * 256, n0 = (c2 % 24) * 128;
  const int lane = tid & 63, wid = tid >> 6;   // wid 0..7
  const int wr = wid >> 1, wc = wid & 1;       // wr 0..3 (64-row bands)
  const int fr = lane & 15, g = lane >> 4;

  const int srow = lane >> 2;
  const int scol = ((lane & 3) ^ ((lane >> 3) & 3)) * 8;
  const unsigned short* gA0 = A + (size_t)(m0 + wid * 16 + srow) * K + scol;
  const unsigned short* gA1 =
      A + (size_t)(m0 + 128 + wid * 16 + srow) * K + scol;
  const unsigned short* gB = Bt + (size_t)(n0 + wid * 16 + srow) * K + scol;
  unsigned short* lAw0 = lA + wid * 16 * 32;
  unsigned short* lAw1 = lA + (128 + wid * 16) * 32;
  unsigned short* lBw = lB + wid * 16 * 32;

  const int rswz = (g ^ ((fr >> 1) & 3)) * 8;

  f32x4 acc[4][4];
#pragma unroll
  for (int i = 0; i < 4; ++i)
#pragma unroll
    for (int j = 0; j < 4; ++j) acc[i][j] = (f32x4){0.f, 0.f, 0.f, 0.f};

  for (int kt = 0; kt < K; kt += 32) {
    gll16(gA0 + kt, lAw0);
    gll16(gA1 + kt, lAw1);
    gll16(gB + kt, lBw);
    __syncthreads();
    bf16x8 af[4], bfv[4];
#pragma unroll
    for (int i = 0; i < 4; ++i)
      af[i] = *reinterpret_cast<const bf16x8*>(
          &lA[(wr * 64 + i * 16 + fr) * 32 + rswz]);
#pragma unroll
    for (int j = 0; j < 4; ++j)
      bfv[j] = *reinterpret_cast<const bf16x8*>(
          &lB[(wc * 64 + j * 16 + fr) * 32 + rswz]);
#pragma unroll
    for (int i = 0; i < 4; ++i)
#pragma unroll
      for (int j = 0; j < 4; ++j)
        acc[i][j] = mfma16(af[i], bfv[j], acc[i][j]);
    __syncthreads();
  }

  const int src = n0 >> 10;  // 0..2, uniform per block
  const float* bp = (src == 0) ? b0 : (src == 1 ? b1 : b2);
#pragma unroll
  for (int i = 0; i < 4; ++i)
#pragma unroll
    for (int j = 0; j < 4; ++j) {
      if (src == 2) {
        const int mb = m0 + wr * 64 + i * 16 + g * 4;
        const int n = n0 + wc * 64 + j * 16 + fr;
        const int within = n & 1023;
        const float bias = bp[within];
        const int b = mb >> 11, s0 = mb & 2047;
        const int hh = within >> 6, dh = within & 63;
        const size_t idx0 =
            ((size_t)(b * NHEADS + hh) * HDIM + dh) * SEQ + s0;
        ushort4 o4;
        o4.x = f2bf(acc[i][j][0] + bias);
        o4.y = f2bf(acc[i][j][1] + bias);
        o4.z = f2bf(acc[i][j][2] + bias);
        o4.w = f2bf(acc[i][j][3] + bias);
        *reinterpret_cast<ushort4*>(outp + 2 * CHELEM + idx0) = o4;
      } else {
#pragma unroll
        for (int r = 0; r < 4; ++r) {
          int m = m0 + wr * 64 + i * 16 + g * 4 + r;
          int n = n0 + wc * 64 + j * 16 + fr;
          int within = n & 1023;
          float val = acc[i][j][r] + bp[within];
          if (src == 0) val *= 0.1803368867f;  // 0.125 * log2(e)
          int b = m >> 11, s = m & 2047;
          int hh = within >> 6, dh = within & 63;
          size_t idx = ((size_t)(b * NHEADS + hh) * SEQ + s) * HDIM + dh;
          outp[(size_t)src * CHELEM + idx] = f2bf(val);
        }
      }
    }
}

// ---------------- Projection GEMM: 64x128 tile, 4 waves, 2048 waves -------
// Grid: 1-D 512 with XCD swizzle (64 contiguous work-items per XCD =
// 8 m-panels x all 8 n-blocks -> A 1MB + B 2MB L2-resident per XCD).
__global__ __launch_bounds__(256) void gemm_proj(
    const unsigned short* __restrict__ A,
    const unsigned short* __restrict__ Bt,
    const float* __restrict__ b0,
    float* __restrict__ outp, int M, int N, int K) {
  __shared__ __align__(16) unsigned short lA[64 * 32];   // 4 KB
  __shared__ __align__(16) unsigned short lB[128 * 32];  // 8 KB
  const int tid = threadIdx.x;
  const int lin = blockIdx.x;
  const int c2 = (lin & 7) * 64 + (lin >> 3);  // 0..511, XCD-chunked
  const int m0 = (c2 / 8) * 64, n0 = (c2 % 8) * 128;
  const int lane = tid & 63, wid = tid >> 6;
  const int fr = lane & 15, g = lane >> 4;

  const int srow = lane >> 2;
  const int scol = ((lane & 3) ^ ((lane >> 3) & 3)) * 8;
  const unsigned short* gA = A + (size_t)(m0 + wid * 16 + srow) * K + scol;
  const unsigned short* gB0 = Bt + (size_t)(n0 + wid * 16 + srow) * K + scol;
  const unsigned short* gB1 = gB0 + (size_t)64 * K;
  unsigned short* lAw = lA + wid * 512;
  unsigned short* lBw0 = lB + wid * 512;
  unsigned short* lBw1 = lB + 2048 + wid * 512;

  const int rswz = (g ^ ((fr >> 1) & 3)) * 8;

  f32x4 acc[4][2];
#pragma unroll
  for (int i = 0; i < 4; ++i)
#pragma unroll
    for (int j = 0; j < 2; ++j) acc[i][j] = (f32x4){0.f, 0.f, 0.f, 0.f};

  for (int kt = 0; kt < K; kt += 32) {
    gll16(gA + kt, lAw);
    gll16(gB0 + kt, lBw0);
    gll16(gB1 + kt, lBw1);
    __syncthreads();
    bf16x8 af[4], bfv[2];
#pragma unroll
    for (int i = 0; i < 4; ++i)
      af[i] = *reinterpret_cast<const bf16x8*>(
          &lA[(i * 16 + fr) * 32 + rswz]);
#pragma unroll
    for (int j = 0; j < 2; ++j)
      bfv[j] = *reinterpret_cast<const bf16x8*>(
          &lB[(wid * 32 + j * 16 + fr) * 32 + rswz]);
#pragma unroll
    for (int i = 0; i < 4; ++i)
#pragma unroll
      for (int j = 0; j < 2; ++j)
        acc[i][j] = mfma16(af[i], bfv[j], acc[i][j]);
    __syncthreads();
  }

#pragma unroll
  for (int i = 0; i < 4; ++i)
#pragma unroll
    for (int j = 0; j < 2; ++j)
#pragma unroll
      for (int r = 0; r < 4; ++r) {
        int m = m0 + i * 16 + g * 4 + r;
        int n = n0 + wid * 32 + j * 16 + fr;
        outp[(size_t)m * N + n] = acc[i][j][r] + b0[n];
      }
}

// Flash attention, swapped-operand, KVBLK=128 (r20-proven, verbatim).
// Q,K: [B,H,S,64] bf16 ; Vt: [B,H,64,S] bf16 ; O: [B,S,1024] bf16
__global__ __launch_bounds__(256) void attn_fwd14(
    const unsigned short* __restrict__ Q,
    const unsigned short* __restrict__ Km,
    const unsigned short* __restrict__ Vt,
    unsigned short* __restrict__ O) {
  const int tid = threadIdx.x;
  const int lane = tid & 63, wid = tid >> 6;
  const int fr = lane & 15, g = lane >> 4;
  const int lin = blockIdx.x;            // 0..511
  const int c = lin & 7;
  const int t = lin >> 3;                // 0..63
  const int j = t & 15;                  // block's pair index 0..15
  const int sgrp = t >> 4;               // 0..3
  const int slab = sgrp * 8 + c;         // 0..31
  const int b = slab >> 4, h = slab & 15;
  const int bh = b * NHEADS + h;

  __shared__ __align__(16) unsigned short lK[2][8192];   // 2 x 16KB
  __shared__ __align__(16) unsigned short lV[2][8192];   // 2 x 16KB

  const unsigned short* kptr = Km + (size_t)bh * SEQ * HDIM;
  const unsigned short* vptr = Vt + (size_t)bh * HDIM * SEQ;

  const int srK = tid >> 3;              // 0..31
  const int schK = (((tid & 7) ^ (srK & 7)) << 3);
  const int srV = tid >> 4;              // 0..15
  const int schV = (((tid & 15) ^ (srV & 7)) << 3);
  const int kswz0 = ((g ^ (fr & 7)) << 3);
  const int kswz1 = (((4 + g) ^ (fr & 7)) << 3);
  const int g2 = g >> 1, gh = (g & 1) * 4;
  const int vlo0 = (((0 + g2) ^ (fr & 7)) << 3) + gh;
  const int vhi0 = (((2 + g2) ^ (fr & 7)) << 3) + gh;
  const int vlo1 = (((4 + g2) ^ (fr & 7)) << 3) + gh;
  const int vhi1 = (((6 + g2) ^ (fr & 7)) << 3) + gh;
  const int vlo2 = (((8 + g2) ^ (fr & 7)) << 3) + gh;
  const int vhi2 = (((10 + g2) ^ (fr & 7)) << 3) + gh;
  const int vlo3 = (((12 + g2) ^ (fr & 7)) << 3) + gh;
  const int vhi3 = (((14 + g2) ^ (fr & 7)) << 3) + gh;

#define STAGE(BI, N0)                                                       \
  { _Pragma("unroll") for (int q = 0; q < 4; ++q) {                         \
      gll16(kptr + (size_t)((N0) + q * 32 + srK) * HDIM + schK,             \
            &lK[BI][q * 2048 + wid * 512]);                                 \
      gll16(vptr + (size_t)(q * 16 + srV) * SEQ + (N0) + schV,              \
            &lV[BI][q * 2048 + wid * 512]);                                 \
    } }

#pragma unroll 1
  for (int pass = 0; pass < 2; ++pass) {
    const int qt = pass ? (124 - 4 * j + wid) : (4 * j + wid);
    const int q0 = qt * 16;
    const int nkt = pass ? (16 - (j >> 1)) : ((j >> 1) + 1);
    const int qg = q0 + fr;

    const unsigned short* qb = Q + ((size_t)bh * SEQ + qg) * HDIM + g * 8;
    bf16x8 qa0 = *reinterpret_cast<const bf16x8*>(qb);
    bf16x8 qa1 = *reinterpret_cast<const bf16x8*>(qb + 32);

    f32x4 oacc[4];
#pragma unroll
    for (int i = 0; i < 4; ++i) oacc[i] = (f32x4){0.f, 0.f, 0.f, 0.f};
    float mreg = -3e30f;
    float lrow = 0.f;

    STAGE(0, 0);
    __syncthreads();

    for (int kt = 0; kt < nkt; ++kt) {
      const int bi = kt & 1;
      if (kt + 1 < nkt) STAGE(bi ^ 1, (kt + 1) * 128);
      const int n0 = kt * 128;
      f32x4 s[8];
#pragma unroll
      for (int cc = 0; cc < 8; ++cc) {
        bf16x8 kf0 = *reinterpret_cast<const bf16x8*>(
            &lK[bi][(cc * 16 + fr) * 64 + kswz0]);
        bf16x8 kf1 = *reinterpret_cast<const bf16x8*>(
            &lK[bi][(cc * 16 + fr) * 64 + kswz1]);
        s[cc] = (f32x4){0.f, 0.f, 0.f, 0.f};
        s[cc] = mfma16(kf0, qa0, s[cc]);
        s[cc] = mfma16(kf1, qa1, s[cc]);
      }
      float sv[8][4];
      float lmax = -3e30f;
      if (kt == nkt - 1) {
#pragma unroll
        for (int cc = 0; cc < 8; ++cc)
#pragma unroll
          for (int r = 0; r < 4; ++r) {
            sv[cc][r] =
                (n0 + cc * 16 + g * 4 + r <= qg) ? s[cc][r] : -1e30f;
            lmax = fmaxf(lmax, sv[cc][r]);
          }
      } else {
#pragma unroll
        for (int cc = 0; cc < 8; ++cc)
#pragma unroll
          for (int r = 0; r < 4; ++r) {
            sv[cc][r] = s[cc][r];
            lmax = fmaxf(lmax, sv[cc][r]);
          }
      }
      if (!__all(lmax - mreg <= 11.5f)) {
        float tm = lmax;
        tm = fmaxf(tm, __shfl_xor(tm, 16, 64));
        tm = fmaxf(tm, __shfl_xor(tm, 32, 64));
        const float mn = fmaxf(mreg, tm);
        const float al = fexp2(mreg - mn);
        mreg = mn;
        lrow *= al;
#pragma unroll
        for (int nf = 0; nf < 4; ++nf) oacc[nf] *= al;
      }
      union { __bf16 e[8]; bf16x8 v; } pkA, pkB, pkC, pkD;
#pragma unroll
      for (int r = 0; r < 4; ++r) {
        float p0 = fexp2(sv[0][r] - mreg);
        float p1 = fexp2(sv[1][r] - mreg);
        float p2 = fexp2(sv[2][r] - mreg);
        float p3 = fexp2(sv[3][r] - mreg);
        float p4 = fexp2(sv[4][r] - mreg);
        float p5 = fexp2(sv[5][r] - mreg);
        float p6 = fexp2(sv[6][r] - mreg);
        float p7 = fexp2(sv[7][r] - mreg);
        lrow += ((p0 + p1) + (p2 + p3)) + ((p4 + p5) + (p6 + p7));
        pkA.e[r] = (__bf16)p0; pkA.e[4 + r] = (__bf16)p1;
        pkB.e[r] = (__bf16)p2; pkB.e[4 + r] = (__bf16)p3;
        pkC.e[r] = (__bf16)p4; pkC.e[4 + r] = (__bf16)p5;
        pkD.e[r] = (__bf16)p6; pkD.e[4 + r] = (__bf16)p7;
      }
#pragma unroll
      for (int nf = 0; nf < 4; ++nf) {
        const int vrow = (nf * 16 + fr) * 128;
        union { unsigned long long d[2]; bf16x8 v; } v0, v1, v2, v3;
        v0.d[0] = *reinterpret_cast<const unsigned long long*>(&lV[bi][vrow + vlo0]);
        v0.d[1] = *reinterpret_cast<const unsigned long long*>(&lV[bi][vrow + vhi0]);
        v1.d[0] = *reinterpret_cast<const unsigned long long*>(&lV[bi][vrow + vlo1]);
        v1.d[1] = *reinterpret_cast<const unsigned long long*>(&lV[bi][vrow + vhi1]);
        v2.d[0] = *reinterpret_cast<const unsigned long long*>(&lV[bi][vrow + vlo2]);
        v2.d[1] = *reinterpret_cast<const unsigned long long*>(&lV[bi][vrow + vhi2]);
        v3.d[0] = *reinterpret_cast<const unsigned long long*>(&lV[bi][vrow + vlo3]);
        v3.d[1] = *reinterpret_cast<const unsigned long long*>(&lV[bi][vrow + vhi3]);
        oacc[nf] = mfma16(v0.v, pkA.v, oacc[nf]);
        oacc[nf] = mfma16(v1.v, pkB.v, oacc[nf]);
        oacc[nf] = mfma16(v2.v, pkC.v, oacc[nf]);
        oacc[nf] = mfma16(v3.v, pkD.v, oacc[nf]);
      }
      __syncthreads();
    }

    float ls = lrow;
    ls += __shfl_xor(ls, 16, 64);
    ls += __shfl_xor(ls, 32, 64);
    const float inv = 1.f / ls;
    const size_t obase = ((size_t)b * SEQ + qg) * D_MODEL + h * HDIM + g * 4;
#pragma unroll
    for (int nf = 0; nf < 4; ++nf) {
      ushort4 o4;
      o4.x = f2bf(oacc[nf][0] * inv);
      o4.y = f2bf(oacc[nf][1] * inv);
      o4.z = f2bf(oacc[nf][2] * inv);
      o4.w = f2bf(oacc[nf][3] * inv);
      *reinterpret_cast<ushort4*>(&O[obase + nf * 16]) = o4;
    }
  }
#undef STAGE
}

extern "C" void kernel_launch(void* const* d_in, const int* in_sizes, int n_in,
                              void* d_out, int out_size, void* d_ws,
                              size_t ws_size, hipStream_t stream) {
  const float* x  = (const float*)d_in[0];
  const float* wq = (const float*)d_in[1];
  const float* bq = (const float*)d_in[2];
  const float* wk = (const float*)d_in[3];
  const float* bk = (const float*)d_in[4];
  const float* wv = (const float*)d_in[5];
  const float* bv = (const float*)d_in[6];
  const float* wo = (const float*)d_in[7];
  const float* bo = (const float*)d_in[8];
  float* out = (float*)d_out;

  char* w = (char*)d_ws;
  unsigned short* xb    = (unsigned short*)w; w += (size_t)MROWS * D_MODEL * 2;
  unsigned short* wqkvb = (unsigned short*)w; w += (size_t)3 * D_MODEL * D_MODEL * 2;
  unsigned short* wob   = (unsigned short*)w; w += (size_t)D_MODEL * D_MODEL * 2;
  unsigned short* Qb    = (unsigned short*)w; w += CHELEM * 2 * 3;  // Q,K,Vt
  unsigned short* Ob    = (unsigned short*)w; w += (size_t)MROWS * D_MODEL * 2;
  unsigned short* Kb  = Qb + CHELEM;
  unsigned short* Vtb = Qb + 2 * CHELEM;

  // single fused conversion pass: weights + x (8 equal slices)
  cvt_all<<<dim3(1024, 8), 256, 0, stream>>>(x, wq, wk, wv, wo, xb, wqkvb, wob);

  // fused QKV projection: N = 3072, 8-wave 256x128 tiles, XCD-swizzled grid
  gemm_qkv<<<384, 512, 0, stream>>>(
      xb, wqkvb, bq, bk, bv, Qb, MROWS, 3 * D_MODEL, D_MODEL);

  attn_fwd14<<<512, 256, 0, stream>>>(Qb, Kb, Vtb, Ob);

  // output projection: 64x128 tiles, XCD-swizzled grid
  gemm_proj<<<512, 256, 0, stream>>>(
      Ob, wob, bo, out, MROWS, D_MODEL, D_MODEL);
}